// Round 2
// baseline (34372.342 us; speedup 1.0000x reference)
//
#include <hip/hip_runtime.h>
#include <stdint.h>
#include <stddef.h>

typedef _Float16 f16;
typedef _Float16 f16x8 __attribute__((ext_vector_type(8)));
typedef float f32x4 __attribute__((ext_vector_type(4)));

#define MFMA16(a, b, c) __builtin_amdgcn_mfma_f32_16x16x32_f16((a), (b), (c), 0, 0, 0)

static constexpr int kB = 64;
static constexpr int kT = 256;
static constexpr int kD = 1024;
static constexpr int kH = 1024;
static constexpr int kL = 4;
static constexpr int kM = kB * kT;   // 16384
static constexpr int kG = 4 * kH;    // 4096
static constexpr int kNWG = 128;     // scan workgroups

// ---------------- f32 -> f16 flat convert (8 elems/thread) ----------------
__global__ void cvt_f32_f16(const float* __restrict__ src, f16* __restrict__ dst) {
  size_t i = ((size_t)blockIdx.x * blockDim.x + threadIdx.x) * 8;
  float4 a = *(const float4*)(src + i);
  float4 b = *(const float4*)(src + i + 4);
  f16x8 o;
  o[0] = (f16)a.x; o[1] = (f16)a.y; o[2] = (f16)a.z; o[3] = (f16)a.w;
  o[4] = (f16)b.x; o[5] = (f16)b.y; o[6] = (f16)b.z; o[7] = (f16)b.w;
  *(f16x8*)(dst + i) = o;
}

// ---- transpose+convert one layer: [1024][4096] f32 -> [4096][1024] f16 ----
__global__ void transpose_cvt(const float* __restrict__ src, f16* __restrict__ dst) {
  __shared__ float tile[32][33];
  int c0 = blockIdx.x * 32;
  int r0 = blockIdx.y * 32;
  for (int rr = threadIdx.y; rr < 32; rr += 8)
    tile[rr][threadIdx.x] = src[(size_t)(r0 + rr) * kG + c0 + threadIdx.x];
  __syncthreads();
  for (int cc = threadIdx.y; cc < 32; cc += 8)
    dst[(size_t)(c0 + cc) * kD + r0 + threadIdx.x] = (f16)tile[threadIdx.x][cc];
}

// ---------------- input projection GEMM: C = A @ Bt^T + bias ----------------
// A: [kM][1024] f16 row-major, Bt: [4096][1024] f16 (N-major, K-contig), C: [kM][4096] f16
__launch_bounds__(256, 2)
__global__ void gemm_xw(const f16* __restrict__ A,
                        const f16* __restrict__ Bt,
                        const float* __restrict__ bias,
                        f16* __restrict__ C) {
  constexpr int K = 1024;
  constexpr int LDS_S = 40;  // 32 + 8 pad -> max 2-way bank aliasing (free)
  __shared__ f16 As[128 * LDS_S];
  __shared__ f16 Bs[128 * LDS_S];
  const int n0 = blockIdx.x * 128;
  const int m0 = blockIdx.y * 128;
  const int tid = threadIdx.x;
  const int l = tid & 63, w = tid >> 6;
  const int lr = l & 15, lq = l >> 4;
  const int wm = (w & 1) * 64, wn = (w >> 1) * 64;

  const int srow = tid >> 1;
  const int skoff = (tid & 1) * 16;
  const f16* Ag = A + (size_t)(m0 + srow) * K + skoff;
  const f16* Bg = Bt + (size_t)(n0 + srow) * K + skoff;
  f16* Asw = &As[srow * LDS_S + skoff];
  f16* Bsw = &Bs[srow * LDS_S + skoff];

  f32x4 acc[4][4] = {};

  f16x8 pa0 = *(const f16x8*)(Ag), pa1 = *(const f16x8*)(Ag + 8);
  f16x8 pb0 = *(const f16x8*)(Bg), pb1 = *(const f16x8*)(Bg + 8);

#pragma unroll 1
  for (int kt = 0; kt < K / 32; ++kt) {
    __syncthreads();
    *(f16x8*)(Asw) = pa0; *(f16x8*)(Asw + 8) = pa1;
    *(f16x8*)(Bsw) = pb0; *(f16x8*)(Bsw + 8) = pb1;
    __syncthreads();
    if (kt + 1 < K / 32) {
      const f16* An = Ag + (kt + 1) * 32;
      const f16* Bn = Bg + (kt + 1) * 32;
      pa0 = *(const f16x8*)(An); pa1 = *(const f16x8*)(An + 8);
      pb0 = *(const f16x8*)(Bn); pb1 = *(const f16x8*)(Bn + 8);
    }
    f16x8 af[4], bf[4];
#pragma unroll
    for (int mt = 0; mt < 4; ++mt)
      af[mt] = *(const f16x8*)(&As[(wm + mt * 16 + lr) * LDS_S + lq * 8]);
#pragma unroll
    for (int nt = 0; nt < 4; ++nt)
      bf[nt] = *(const f16x8*)(&Bs[(wn + nt * 16 + lr) * LDS_S + lq * 8]);
#pragma unroll
    for (int mt = 0; mt < 4; ++mt)
#pragma unroll
      for (int nt = 0; nt < 4; ++nt)
        acc[mt][nt] = MFMA16(af[mt], bf[nt], acc[mt][nt]);
  }

#pragma unroll
  for (int nt = 0; nt < 4; ++nt) {
    const int col = n0 + wn + nt * 16 + lr;
    const float bv = bias[col];
#pragma unroll
    for (int mt = 0; mt < 4; ++mt) {
#pragma unroll
      for (int j = 0; j < 4; ++j) {
        const int row = m0 + wm + mt * 16 + lq * 4 + j;
        C[(size_t)row * kG + col] = (f16)(acc[mt][nt][j] + bv);
      }
    }
  }
}

// ---------------- persistent LSTM scan over T steps ----------------
// 128 WGs x 256 thr. WG wg owns h-units [wg*8, wg*8+8) -> 32 gate columns.
// U slice lives in registers (64 x f16x8 = 256 VGPR). h ping-pong in global f16.
// Residency: capacity >= 1 WG/CU * 256 CUs >= 128 WGs, so the epoch barrier
// cannot deadlock (all participants co-resident once dispatched).
__launch_bounds__(256, 1)
__global__ void lstm_scan(const f16* __restrict__ xz,    // [kM][4096] f16
                          const f16* __restrict__ Ut,    // [4096][1024] f16
                          f16* __restrict__ hA,
                          f16* __restrict__ hB,
                          f16* __restrict__ seq_out,     // [kM][1024] f16 or null
                          float* __restrict__ out32,     // [kM*1024] f32 or null
                          int* __restrict__ bar) {
  const int wg = blockIdx.x;
  const int hbase = wg * 8;
  const int tid = threadIdx.x, l = tid & 63, w = tid >> 6;
  const int lr = l & 15, lq = l >> 4;
  const int brow = w * 16 + lq * 4;       // C-frag base row (batch index)
  const int ugl = hbase + (lr & 7);       // h-unit this lane finalizes

  // --- U fragments -> registers ---
  // ub0 rows 0-15: gates {i (lr<8), f (lr>=8)}; ub1 rows 16-31: {g, o}
  f16x8 ub0[32], ub1[32];
  {
    const int r0 = lr;
    const int r1 = 16 + lr;
    const size_t grow0 = (size_t)((r0 >> 3) * 1024 + hbase + (r0 & 7));
    const size_t grow1 = (size_t)((r1 >> 3) * 1024 + hbase + (r1 & 7));
    const f16* p0 = Ut + grow0 * 1024 + lq * 8;
    const f16* p1 = Ut + grow1 * 1024 + lq * 8;
#pragma unroll
    for (int kk = 0; kk < 32; ++kk) {
      ub0[kk] = *(const f16x8*)(p0 + kk * 32);
      ub1[kk] = *(const f16x8*)(p1 + kk * 32);
    }
  }

  const int col0 = (lr < 8) ? (hbase + lr) : (1024 + hbase + (lr - 8));
  const int col1 = (lr < 8) ? (2048 + hbase + lr) : (3072 + hbase + (lr - 8));

  float c_reg[4] = {0.f, 0.f, 0.f, 0.f};

#pragma unroll 1
  for (int t = 0; t < kT; ++t) {
    const f16* hin = (t & 1) ? hB : hA;
    f16* hout = (t & 1) ? hA : hB;

    // xz prefetch (independent of h; latency hides under the K-loop)
    float xz0[4], xz1[4];
#pragma unroll
    for (int j = 0; j < 4; ++j) {
      const size_t row = (size_t)(brow + j) * kT + t;
      xz0[j] = (float)xz[row * kG + col0];
      xz1[j] = (float)xz[row * kG + col1];
    }

    // z = h_{t-1} @ U  (4 independent MFMA chains)
    f32x4 a0c = {}, a1c = {}, b0c = {}, b1c = {};
    const f16* hrow = hin + (size_t)(w * 16 + lr) * kH + lq * 8;
#pragma unroll
    for (int kk = 0; kk < 32; kk += 2) {
      f16x8 ha = *(const f16x8*)(hrow + kk * 32);
      f16x8 hb2 = *(const f16x8*)(hrow + kk * 32 + 32);
      a0c = MFMA16(ha, ub0[kk], a0c);
      a1c = MFMA16(ha, ub1[kk], a1c);
      b0c = MFMA16(hb2, ub0[kk + 1], b0c);
      b1c = MFMA16(hb2, ub1[kk + 1], b1c);
    }

    float hv[4];
#pragma unroll
    for (int j = 0; j < 4; ++j) {
      const float z0 = a0c[j] + b0c[j] + xz0[j];
      const float z1 = a1c[j] + b1c[j] + xz1[j];
      const float q0 = __shfl_xor(z0, 8);
      const float q1 = __shfl_xor(z1, 8);
      const float zi = (lr & 8) ? q0 : z0;
      const float zf = (lr & 8) ? z0 : q0;
      const float zg = (lr & 8) ? q1 : z1;
      const float zo = (lr & 8) ? z1 : q1;
      const float iv = 1.f / (1.f + __expf(-zi));
      const float fv = 1.f / (1.f + __expf(-zf));
      const float gv = tanhf(zg);
      const float ov = 1.f / (1.f + __expf(-zo));
      const float cn = fv * c_reg[j] + iv * gv;
      c_reg[j] = cn;
      hv[j] = ov * tanhf(cn);
    }

    if (lr < 8) {
#pragma unroll
      for (int j = 0; j < 4; ++j) {
        const int b = brow + j;
        const f16 hh = (f16)hv[j];
        hout[(size_t)b * kH + ugl] = hh;
        if (seq_out) seq_out[((size_t)b * kT + t) * kH + ugl] = hh;
        if (out32) out32[((size_t)b * kT + t) * kH + ugl] = hv[j];
      }
    }

    if (t + 1 < kT) {
      __threadfence();       // release: write back this XCD's L2 (cross-XCD vis)
      __syncthreads();       // all waves of this WG fenced
      if (tid == 0) {
        __hip_atomic_fetch_add(bar, 1, __ATOMIC_RELEASE, __HIP_MEMORY_SCOPE_AGENT);
        const int target = kNWG * (t + 1);
        while (__hip_atomic_load(bar, __ATOMIC_ACQUIRE, __HIP_MEMORY_SCOPE_AGENT) < target)
          __builtin_amdgcn_s_sleep(1);
      }
      __syncthreads();
      __threadfence();       // acquire: invalidate stale L1/L2 before reading h
    }
  }
}

// ---------------- host launch ----------------
extern "C" void kernel_launch(void* const* d_in, const int* in_sizes, int n_in,
                              void* d_out, int out_size, void* d_ws, size_t ws_size,
                              hipStream_t stream) {
  (void)in_sizes; (void)n_in; (void)out_size; (void)ws_size;
  const float* x = (const float*)d_in[0];
  const float* Ws = (const float*)d_in[1];
  const float* Us = (const float*)d_in[2];
  const float* bs = (const float*)d_in[3];
  char* ws = (char*)d_ws;

  // Workspace layout (total 218,366,208 B ~= 208.3 MB)
  const size_t WT_OFF = 0;                                  // per-layer Wt (8 MB)
  const size_t UT_OFF = WT_OFF + (size_t)kG * kD * 2;       // per-layer Ut (8 MB)
  const size_t SA_OFF = UT_OFF + (size_t)kG * kD * 2;       // seq ping (32 MB)
  const size_t SB_OFF = SA_OFF + (size_t)kM * kD * 2;       // seq pong (32 MB)
  const size_t XZ_OFF = SB_OFF + (size_t)kM * kD * 2;       // xz (128 MB)
  const size_t HA_OFF = XZ_OFF + (size_t)kM * kG * 2;       // h ping (128 KB)
  const size_t HB_OFF = HA_OFF + (size_t)kB * kH * 2;       // h pong (128 KB)
  const size_t BAR_OFF = HB_OFF + (size_t)kB * kH * 2;      // barrier counter

  f16* Wt = (f16*)(ws + WT_OFF);
  f16* Ut = (f16*)(ws + UT_OFF);
  f16* sA = (f16*)(ws + SA_OFF);
  f16* sB = (f16*)(ws + SB_OFF);
  f16* xz = (f16*)(ws + XZ_OFF);
  f16* hA = (f16*)(ws + HA_OFF);
  f16* hB = (f16*)(ws + HB_OFF);
  int* bar = (int*)(ws + BAR_OFF);

  cvt_f32_f16<<<kM * kD / (256 * 8), 256, 0, stream>>>(x, sA);

  f16* sin_ = sA;
  f16* sout_ = sB;
  for (int lyr = 0; lyr < kL; ++lyr) {
    transpose_cvt<<<dim3(kG / 32, kD / 32), dim3(32, 8), 0, stream>>>(
        Ws + (size_t)lyr * kD * kG, Wt);
    transpose_cvt<<<dim3(kG / 32, kD / 32), dim3(32, 8), 0, stream>>>(
        Us + (size_t)lyr * kH * kG, Ut);
    gemm_xw<<<dim3(kG / 128, kM / 128), 256, 0, stream>>>(
        sin_, Wt, bs + (size_t)lyr * kG, xz);
    // zero h ping-pong buffers + barrier counter (contiguous region)
    hipMemsetAsync(ws + HA_OFF, 0, (size_t)kB * kH * 2 * 2 + 256, stream);
    lstm_scan<<<kNWG, 256, 0, stream>>>(
        xz, Ut, hA, hB,
        (lyr < kL - 1) ? sout_ : (f16*)nullptr,
        (lyr == kL - 1) ? (float*)d_out : (float*)nullptr, bar);
    f16* tmp = sin_; sin_ = sout_; sout_ = tmp;
  }
}

// Round 3
// 10371.180 us; speedup vs baseline: 3.3142x; 3.3142x over previous
//
#include <hip/hip_runtime.h>
#include <stdint.h>
#include <stddef.h>

typedef _Float16 f16;
typedef _Float16 f16x8 __attribute__((ext_vector_type(8)));
typedef float f32x4 __attribute__((ext_vector_type(4)));

#define MFMA16(a, b, c) __builtin_amdgcn_mfma_f32_16x16x32_f16((a), (b), (c), 0, 0, 0)

static constexpr int kB = 64;
static constexpr int kT = 256;
static constexpr int kD = 1024;
static constexpr int kH = 1024;
static constexpr int kL = 4;
static constexpr int kM = kB * kT;   // 16384
static constexpr int kG = 4 * kH;    // 4096
static constexpr int kNWG = 128;     // scan workgroups

// ---------------- f32 -> f16 flat convert (8 elems/thread) ----------------
__global__ void cvt_f32_f16(const float* __restrict__ src, f16* __restrict__ dst) {
  size_t i = ((size_t)blockIdx.x * blockDim.x + threadIdx.x) * 8;
  float4 a = *(const float4*)(src + i);
  float4 b = *(const float4*)(src + i + 4);
  f16x8 o;
  o[0] = (f16)a.x; o[1] = (f16)a.y; o[2] = (f16)a.z; o[3] = (f16)a.w;
  o[4] = (f16)b.x; o[5] = (f16)b.y; o[6] = (f16)b.z; o[7] = (f16)b.w;
  *(f16x8*)(dst + i) = o;
}

// ---- transpose+convert one layer: [1024][4096] f32 -> [4096][1024] f16 ----
__global__ void transpose_cvt(const float* __restrict__ src, f16* __restrict__ dst) {
  __shared__ float tile[32][33];
  int c0 = blockIdx.x * 32;
  int r0 = blockIdx.y * 32;
  for (int rr = threadIdx.y; rr < 32; rr += 8)
    tile[rr][threadIdx.x] = src[(size_t)(r0 + rr) * kG + c0 + threadIdx.x];
  __syncthreads();
  for (int cc = threadIdx.y; cc < 32; cc += 8)
    dst[(size_t)(c0 + cc) * kD + r0 + threadIdx.x] = (f16)tile[threadIdx.x][cc];
}

// ---------------- input projection GEMM: C = A @ Bt^T + bias ----------------
__launch_bounds__(256, 2)
__global__ void gemm_xw(const f16* __restrict__ A,
                        const f16* __restrict__ Bt,
                        const float* __restrict__ bias,
                        f16* __restrict__ C) {
  constexpr int K = 1024;
  constexpr int LDS_S = 40;
  __shared__ f16 As[128 * LDS_S];
  __shared__ f16 Bs[128 * LDS_S];
  const int n0 = blockIdx.x * 128;
  const int m0 = blockIdx.y * 128;
  const int tid = threadIdx.x;
  const int l = tid & 63, w = tid >> 6;
  const int lr = l & 15, lq = l >> 4;
  const int wm = (w & 1) * 64, wn = (w >> 1) * 64;

  const int srow = tid >> 1;
  const int skoff = (tid & 1) * 16;
  const f16* Ag = A + (size_t)(m0 + srow) * K + skoff;
  const f16* Bg = Bt + (size_t)(n0 + srow) * K + skoff;
  f16* Asw = &As[srow * LDS_S + skoff];
  f16* Bsw = &Bs[srow * LDS_S + skoff];

  f32x4 acc[4][4] = {};

  f16x8 pa0 = *(const f16x8*)(Ag), pa1 = *(const f16x8*)(Ag + 8);
  f16x8 pb0 = *(const f16x8*)(Bg), pb1 = *(const f16x8*)(Bg + 8);

#pragma unroll 1
  for (int kt = 0; kt < K / 32; ++kt) {
    __syncthreads();
    *(f16x8*)(Asw) = pa0; *(f16x8*)(Asw + 8) = pa1;
    *(f16x8*)(Bsw) = pb0; *(f16x8*)(Bsw + 8) = pb1;
    __syncthreads();
    if (kt + 1 < K / 32) {
      const f16* An = Ag + (kt + 1) * 32;
      const f16* Bn = Bg + (kt + 1) * 32;
      pa0 = *(const f16x8*)(An); pa1 = *(const f16x8*)(An + 8);
      pb0 = *(const f16x8*)(Bn); pb1 = *(const f16x8*)(Bn + 8);
    }
    f16x8 af[4], bf[4];
#pragma unroll
    for (int mt = 0; mt < 4; ++mt)
      af[mt] = *(const f16x8*)(&As[(wm + mt * 16 + lr) * LDS_S + lq * 8]);
#pragma unroll
    for (int nt = 0; nt < 4; ++nt)
      bf[nt] = *(const f16x8*)(&Bs[(wn + nt * 16 + lr) * LDS_S + lq * 8]);
#pragma unroll
    for (int mt = 0; mt < 4; ++mt)
#pragma unroll
      for (int nt = 0; nt < 4; ++nt)
        acc[mt][nt] = MFMA16(af[mt], bf[nt], acc[mt][nt]);
  }

#pragma unroll
  for (int nt = 0; nt < 4; ++nt) {
    const int col = n0 + wn + nt * 16 + lr;
    const float bv = bias[col];
#pragma unroll
    for (int mt = 0; mt < 4; ++mt) {
#pragma unroll
      for (int j = 0; j < 4; ++j) {
        const int row = m0 + wm + mt * 16 + lq * 4 + j;
        C[(size_t)row * kG + col] = (f16)(acc[mt][nt][j] + bv);
      }
    }
  }
}

// ---------------- persistent LSTM scan v2 ----------------
// 128 WGs x 1024 thr (16 waves: 4 batch-groups x 4 K-split groups).
// WG owns 8 h-units (32 gate cols). U slice (64 KB) in LDS, staged once.
// h exchanged through die-shared L3 via sc0 sc1 loads/stores (L2 bypass)
// -> NO cache flushes/fences anywhere in the step loop.
#define HLOAD(dst, base, imm)                                               \
  asm volatile("global_load_dwordx4 %0, %1, off offset:" #imm " sc0 sc1"    \
               : "=v"(dst) : "v"(base) : "memory")

__launch_bounds__(1024, 1)
__global__ void lstm_scan(const f16* __restrict__ xz,    // [kM][4096] f16
                          const f16* __restrict__ Ut,    // [4096][1024] f16
                          f16* __restrict__ hA,
                          f16* __restrict__ hB,
                          f16* __restrict__ seq_out,     // [kM][1024] f16 or null
                          float* __restrict__ out32,     // [kM*1024] f32 or null
                          int* __restrict__ bar) {
  // LDS: 64 KB U + 2x16 KB reduction = 96 KB -> exactly 1 WG/CU.
  __shared__ f16 Ul[4096 * 8];
  __shared__ float red0[16 * 64 * 4];
  __shared__ float red1[16 * 64 * 4];

  const int wg = blockIdx.x;
  const int hbase = wg * 8;
  const int tid = threadIdx.x;
  const int l = tid & 63, w = tid >> 6;
  const int lr = l & 15, lq = l >> 4;
  const int bw = w & 3;     // batch group: rows bw*16..bw*16+15
  const int kw = w >> 2;    // K group: k in [kw*256, kw*256+256)

  // ---- stage U fragments into LDS (once) ----
  // fragment f: x=f>>11 (ub0/ub1), kk=(f>>6)&31, lane=f&63; stored at Ul[f*8].
#pragma unroll
  for (int ff = 0; ff < 4; ++ff) {
    const int f = tid * 4 + ff;
    const int x = f >> 11, kk = (f >> 6) & 31, fl = f & 63;
    const int flr = fl & 15, flq = fl >> 4;
    const int r = x * 16 + flr;
    const size_t grow = (size_t)((r >> 3) * 1024 + hbase + (r & 7));
    *(f16x8*)&Ul[f * 8] = *(const f16x8*)(Ut + grow * 1024 + kk * 32 + flq * 8);
  }
  __syncthreads();

  const int brow = bw * 16 + lq * 4;
  const int ugl = hbase + (lr & 7);
  const int col0 = (lr < 8) ? (hbase + lr) : (1024 + hbase + (lr - 8));
  const int col1 = (lr < 8) ? (2048 + hbase + lr) : (3072 + hbase + (lr - 8));

  float c_reg[4] = {0.f, 0.f, 0.f, 0.f};
  float xz0[4], xz1[4];

  if (kw == 0) {
#pragma unroll
    for (int j = 0; j < 4; ++j) {
      const size_t row = (size_t)(brow + j) * kT;   // t = 0
      xz0[j] = (float)xz[row * kG + col0];
      xz1[j] = (float)xz[row * kG + col1];
    }
  }

#pragma unroll 1
  for (int t = 0; t < kT; ++t) {
    const f16* hin = (t & 1) ? hB : hA;
    f16* hout = (t & 1) ? hA : hB;

    // ---- h loads (L2-bypassing, from L3) ----
    const f16* hp = hin + (size_t)(bw * 16 + lr) * kH + kw * 256 + lq * 8;
    f16x8 ha0, ha1, ha2, ha3, ha4, ha5, ha6, ha7;
    HLOAD(ha0, hp, 0);   HLOAD(ha1, hp, 64);  HLOAD(ha2, hp, 128);
    HLOAD(ha3, hp, 192); HLOAD(ha4, hp, 256); HLOAD(ha5, hp, 320);
    HLOAD(ha6, hp, 384); HLOAD(ha7, hp, 448);
    asm volatile("s_waitcnt vmcnt(0)" ::: "memory");
    __builtin_amdgcn_sched_barrier(0);

    // ---- partial z for this K-chunk: 16 MFMAs ----
    f32x4 acc0 = {}, acc1 = {};
    const int kkb = kw * 8;
#define KSTEP(ii, hareg)                                                     \
    {                                                                        \
      const f16x8 b0 = *(const f16x8*)&Ul[((kkb + ii) * 64 + l) * 8];        \
      const f16x8 b1 = *(const f16x8*)&Ul[((2048 + (kkb + ii) * 64) + l) * 8];\
      acc0 = MFMA16(hareg, b0, acc0);                                        \
      acc1 = MFMA16(hareg, b1, acc1);                                        \
    }
    KSTEP(0, ha0) KSTEP(1, ha1) KSTEP(2, ha2) KSTEP(3, ha3)
    KSTEP(4, ha4) KSTEP(5, ha5) KSTEP(6, ha6) KSTEP(7, ha7)
#undef KSTEP

    // ---- K-split reduction through LDS ----
    *(f32x4*)&red0[tid * 4] = acc0;
    *(f32x4*)&red1[tid * 4] = acc1;
    __syncthreads();

    if (kw == 0) {
      f32x4 s0 = {}, s1 = {};
#pragma unroll
      for (int q = 0; q < 4; ++q) {
        s0 += *(const f32x4*)&red0[((q * 4 + bw) * 64 + l) * 4];
        s1 += *(const f32x4*)&red1[((q * 4 + bw) * 64 + l) * 4];
      }

      float hv[4];
#pragma unroll
      for (int j = 0; j < 4; ++j) {
        const float z0 = s0[j] + xz0[j];
        const float z1 = s1[j] + xz1[j];
        const float q0 = __shfl_xor(z0, 8);
        const float q1 = __shfl_xor(z1, 8);
        const float zi = (lr & 8) ? q0 : z0;
        const float zf = (lr & 8) ? z0 : q0;
        const float zg = (lr & 8) ? q1 : z1;
        const float zo = (lr & 8) ? z1 : q1;
        const float iv = 1.f / (1.f + __expf(-zi));
        const float fv = 1.f / (1.f + __expf(-zf));
        const float gv = tanhf(zg);
        const float ov = 1.f / (1.f + __expf(-zo));
        const float cn = fv * c_reg[j] + iv * gv;
        c_reg[j] = cn;
        hv[j] = ov * tanhf(cn);
      }

      if (lr < 8) {
#pragma unroll
        for (int j = 0; j < 4; ++j) {
          const int b = brow + j;
          const f16 hh = (f16)hv[j];
          const unsigned bits = (unsigned)__builtin_bit_cast(unsigned short, hh);
          f16* hp_out = hout + (size_t)b * kH + ugl;
          asm volatile("global_store_short %0, %1, off sc0 sc1"
                       :: "v"(hp_out), "v"(bits) : "memory");
          if (seq_out) seq_out[((size_t)b * kT + t) * kH + ugl] = hh;
          if (out32) out32[((size_t)b * kT + t) * kH + ugl] = hv[j];
        }
      }

      // prefetch xz for t+1 (cached; latency overlaps the barrier)
      if (t + 1 < kT) {
#pragma unroll
        for (int j = 0; j < 4; ++j) {
          const size_t row = (size_t)(brow + j) * kT + (t + 1);
          xz0[j] = (float)xz[row * kG + col0];
          xz1[j] = (float)xz[row * kG + col1];
        }
      }
      // drain my h stores (and prefetch) before signaling
      asm volatile("s_waitcnt vmcnt(0)" ::: "memory");
    }

    // ---- device-wide epoch barrier (no cache flushes) ----
    if (t + 1 < kT) {
      __syncthreads();
      if (tid == 0) {
        __hip_atomic_fetch_add(bar, 1, __ATOMIC_RELAXED, __HIP_MEMORY_SCOPE_AGENT);
        const int target = kNWG * (t + 1);
        while (__hip_atomic_load(bar, __ATOMIC_RELAXED, __HIP_MEMORY_SCOPE_AGENT) < target)
          __builtin_amdgcn_s_sleep(2);
      }
      __syncthreads();
    }
  }
}

// ---------------- host launch ----------------
extern "C" void kernel_launch(void* const* d_in, const int* in_sizes, int n_in,
                              void* d_out, int out_size, void* d_ws, size_t ws_size,
                              hipStream_t stream) {
  (void)in_sizes; (void)n_in; (void)out_size; (void)ws_size;
  const float* x = (const float*)d_in[0];
  const float* Ws = (const float*)d_in[1];
  const float* Us = (const float*)d_in[2];
  const float* bs = (const float*)d_in[3];
  char* ws = (char*)d_ws;

  const size_t WT_OFF = 0;                                  // per-layer Wt (8 MB)
  const size_t UT_OFF = WT_OFF + (size_t)kG * kD * 2;       // per-layer Ut (8 MB)
  const size_t SA_OFF = UT_OFF + (size_t)kG * kD * 2;       // seq ping (32 MB)
  const size_t SB_OFF = SA_OFF + (size_t)kM * kD * 2;       // seq pong (32 MB)
  const size_t XZ_OFF = SB_OFF + (size_t)kM * kD * 2;       // xz (128 MB)
  const size_t HA_OFF = XZ_OFF + (size_t)kM * kG * 2;       // h ping (128 KB)
  const size_t HB_OFF = HA_OFF + (size_t)kB * kH * 2;       // h pong (128 KB)
  const size_t BAR_OFF = HB_OFF + (size_t)kB * kH * 2;      // barrier counter

  f16* Wt = (f16*)(ws + WT_OFF);
  f16* Ut = (f16*)(ws + UT_OFF);
  f16* sA = (f16*)(ws + SA_OFF);
  f16* sB = (f16*)(ws + SB_OFF);
  f16* xz = (f16*)(ws + XZ_OFF);
  f16* hA = (f16*)(ws + HA_OFF);
  f16* hB = (f16*)(ws + HB_OFF);
  int* bar = (int*)(ws + BAR_OFF);

  cvt_f32_f16<<<kM * kD / (256 * 8), 256, 0, stream>>>(x, sA);

  f16* sin_ = sA;
  f16* sout_ = sB;
  for (int lyr = 0; lyr < kL; ++lyr) {
    transpose_cvt<<<dim3(kG / 32, kD / 32), dim3(32, 8), 0, stream>>>(
        Ws + (size_t)lyr * kD * kG, Wt);
    transpose_cvt<<<dim3(kG / 32, kD / 32), dim3(32, 8), 0, stream>>>(
        Us + (size_t)lyr * kH * kG, Ut);
    gemm_xw<<<dim3(kG / 128, kM / 128), 256, 0, stream>>>(
        sin_, Wt, bs + (size_t)lyr * kG, xz);
    hipMemsetAsync(ws + HA_OFF, 0, (size_t)kB * kH * 2 * 2 + 256, stream);
    lstm_scan<<<kNWG, 1024, 0, stream>>>(
        xz, Ut, hA, hB,
        (lyr < kL - 1) ? sout_ : (f16*)nullptr,
        (lyr == kL - 1) ? (float*)d_out : (float*)nullptr, bar);
    f16* tmp = sin_; sin_ = sout_; sout_ = tmp;
  }
}

// Round 4
// 8418.831 us; speedup vs baseline: 4.0828x; 1.2319x over previous
//
#include <hip/hip_runtime.h>
#include <stdint.h>
#include <stddef.h>

typedef _Float16 f16;
typedef _Float16 f16x8 __attribute__((ext_vector_type(8)));
typedef float f32x4 __attribute__((ext_vector_type(4)));

#define MFMA16(a, b, c) __builtin_amdgcn_mfma_f32_16x16x32_f16((a), (b), (c), 0, 0, 0)

static constexpr int kB = 64;
static constexpr int kT = 256;
static constexpr int kD = 1024;
static constexpr int kH = 1024;
static constexpr int kL = 4;
static constexpr int kM = kB * kT;   // 16384
static constexpr int kG = 4 * kH;    // 4096
static constexpr int kNWG = 128;     // scan workgroups

__device__ __forceinline__ float fast_sigmoid(float x) {
  return __builtin_amdgcn_rcpf(1.f + __expf(-x));
}
__device__ __forceinline__ float fast_tanh(float x) {
  x = fminf(9.f, fmaxf(-9.f, x));
  const float e = __expf(2.f * x);
  return (e - 1.f) * __builtin_amdgcn_rcpf(e + 1.f);
}

// ---------------- f32 -> f16 flat convert (8 elems/thread) ----------------
__global__ void cvt_f32_f16(const float* __restrict__ src, f16* __restrict__ dst) {
  size_t i = ((size_t)blockIdx.x * blockDim.x + threadIdx.x) * 8;
  float4 a = *(const float4*)(src + i);
  float4 b = *(const float4*)(src + i + 4);
  f16x8 o;
  o[0] = (f16)a.x; o[1] = (f16)a.y; o[2] = (f16)a.z; o[3] = (f16)a.w;
  o[4] = (f16)b.x; o[5] = (f16)b.y; o[6] = (f16)b.z; o[7] = (f16)b.w;
  *(f16x8*)(dst + i) = o;
}

// ---- transpose+convert one layer: [1024][4096] f32 -> [4096][1024] f16 ----
__global__ void transpose_cvt(const float* __restrict__ src, f16* __restrict__ dst) {
  __shared__ float tile[32][33];
  int c0 = blockIdx.x * 32;
  int r0 = blockIdx.y * 32;
  for (int rr = threadIdx.y; rr < 32; rr += 8)
    tile[rr][threadIdx.x] = src[(size_t)(r0 + rr) * kG + c0 + threadIdx.x];
  __syncthreads();
  for (int cc = threadIdx.y; cc < 32; cc += 8)
    dst[(size_t)(c0 + cc) * kD + r0 + threadIdx.x] = (f16)tile[threadIdx.x][cc];
}

// ---------------- input projection GEMM: xz = A @ Bt^T + bias ----------------
// A: [kM][1024] f16, Bt: [4096][1024] f16. Output written PERMUTED for the scan:
// xzp[wg][t][b][g*8+hh]  (wg=col&1023>>3, g=col>>10, hh=col&7; b=row>>8, t=row&255)
__launch_bounds__(256, 2)
__global__ void gemm_xw(const f16* __restrict__ A,
                        const f16* __restrict__ Bt,
                        const float* __restrict__ bias,
                        f16* __restrict__ xzp) {
  constexpr int K = 1024;
  constexpr int LDS_S = 40;
  __shared__ f16 As[128 * LDS_S];
  __shared__ f16 Bs[128 * LDS_S];
  const int n0 = blockIdx.x * 128;
  const int m0 = blockIdx.y * 128;
  const int tid = threadIdx.x;
  const int l = tid & 63, w = tid >> 6;
  const int lr = l & 15, lq = l >> 4;
  const int wm = (w & 1) * 64, wn = (w >> 1) * 64;

  const int srow = tid >> 1;
  const int skoff = (tid & 1) * 16;
  const f16* Ag = A + (size_t)(m0 + srow) * K + skoff;
  const f16* Bg = Bt + (size_t)(n0 + srow) * K + skoff;
  f16* Asw = &As[srow * LDS_S + skoff];
  f16* Bsw = &Bs[srow * LDS_S + skoff];

  f32x4 acc[4][4] = {};

  f16x8 pa0 = *(const f16x8*)(Ag), pa1 = *(const f16x8*)(Ag + 8);
  f16x8 pb0 = *(const f16x8*)(Bg), pb1 = *(const f16x8*)(Bg + 8);

#pragma unroll 1
  for (int kt = 0; kt < K / 32; ++kt) {
    __syncthreads();
    *(f16x8*)(Asw) = pa0; *(f16x8*)(Asw + 8) = pa1;
    *(f16x8*)(Bsw) = pb0; *(f16x8*)(Bsw + 8) = pb1;
    __syncthreads();
    if (kt + 1 < K / 32) {
      const f16* An = Ag + (kt + 1) * 32;
      const f16* Bn = Bg + (kt + 1) * 32;
      pa0 = *(const f16x8*)(An); pa1 = *(const f16x8*)(An + 8);
      pb0 = *(const f16x8*)(Bn); pb1 = *(const f16x8*)(Bn + 8);
    }
    f16x8 af[4], bf[4];
#pragma unroll
    for (int mt = 0; mt < 4; ++mt)
      af[mt] = *(const f16x8*)(&As[(wm + mt * 16 + lr) * LDS_S + lq * 8]);
#pragma unroll
    for (int nt = 0; nt < 4; ++nt)
      bf[nt] = *(const f16x8*)(&Bs[(wn + nt * 16 + lr) * LDS_S + lq * 8]);
#pragma unroll
    for (int mt = 0; mt < 4; ++mt)
#pragma unroll
      for (int nt = 0; nt < 4; ++nt)
        acc[mt][nt] = MFMA16(af[mt], bf[nt], acc[mt][nt]);
  }

#pragma unroll
  for (int nt = 0; nt < 4; ++nt) {
    const int col = n0 + wn + nt * 16 + lr;
    const float bv = bias[col];
    const int g = col >> 10, u = col & 1023;
    const int wgi = u >> 3;
    const int goff = (g << 3) | (u & 7);
#pragma unroll
    for (int mt = 0; mt < 4; ++mt) {
#pragma unroll
      for (int j = 0; j < 4; ++j) {
        const int row = m0 + wm + mt * 16 + lq * 4 + j;
        const int b = row >> 8, tt = row & 255;
        xzp[(((size_t)wgi * kT + tt) * 64 + b) * 32 + goff] =
            (f16)(acc[mt][nt][j] + bv);
      }
    }
  }
}

// ---------------- persistent LSTM scan v3 ----------------
// 128 WGs x 1024 thr (16 waves: 4 batch-groups x 4 K-split groups).
// WG owns 8 h-units (32 gate cols). U slice (64 KB) in LDS, staged once.
// xz double-buffered in LDS, prefetched 1 step ahead by kw==1 waves.
// h exchanged through coherent point via sc0 sc1 (no fences anywhere).
#define HLOAD(dst, base, imm)                                               \
  asm volatile("global_load_dwordx4 %0, %1, off offset:" #imm " sc0 sc1"    \
               : "=v"(dst) : "v"(base) : "memory")

__launch_bounds__(1024, 1)
__global__ void lstm_scan(const f16* __restrict__ xzp,   // permuted xz
                          const f16* __restrict__ Ut,    // [4096][1024] f16
                          f16* __restrict__ hA,
                          f16* __restrict__ hB,
                          f16* __restrict__ seq_out,     // [kM][1024] f16 or null
                          float* __restrict__ out32,     // [kM*1024] f32 or null
                          int* __restrict__ bar) {
  // LDS: 64 KB U + 2x16 KB reduction + 8 KB xz dbuf = 104 KB -> 1 WG/CU.
  __shared__ f16 Ul[4096 * 8];
  __shared__ float red0[16 * 64 * 4];
  __shared__ float red1[16 * 64 * 4];
  __shared__ f16 xzb[2][2048];

  const int wg = blockIdx.x;
  const int hbase = wg * 8;
  const int tid = threadIdx.x;
  const int l = tid & 63, w = tid >> 6;
  const int lr = l & 15, lq = l >> 4;
  const int bw = w & 3;     // batch group: rows bw*16..bw*16+15
  const int kw = w >> 2;    // K group: k in [kw*256, kw*256+256)

  // ---- stage U fragments into LDS (once) ----
#pragma unroll
  for (int ff = 0; ff < 4; ++ff) {
    const int f = tid * 4 + ff;
    const int x = f >> 11, kk = (f >> 6) & 31, fl = f & 63;
    const int flr = fl & 15, flq = fl >> 4;
    const int r = x * 16 + flr;
    const size_t grow = (size_t)((r >> 3) * 1024 + hbase + (r & 7));
    *(f16x8*)&Ul[f * 8] = *(const f16x8*)(Ut + grow * 1024 + kk * 32 + flq * 8);
  }
  // ---- stage xz(t=0) into LDS buffer 0 ----
  const int pidx = (w - 4) * 64 + l;    // valid for kw==1 waves: 0..255
  if (kw == 1) {
    *(f16x8*)&xzb[0][pidx * 8] =
        *(const f16x8*)(xzp + ((size_t)wg * kT + 0) * 2048 + pidx * 8);
  }
  __syncthreads();

  const int brow = bw * 16 + lq * 4;
  const int ugl = hbase + (lr & 7);

  float c_reg[4] = {0.f, 0.f, 0.f, 0.f};

#pragma unroll 1
  for (int t = 0; t < kT; ++t) {
    const f16* hin = (t & 1) ? hB : hA;
    f16* hout = (t & 1) ? hA : hB;

    // ---- h loads (coherent, from L3) ----
    const f16* hp = hin + (size_t)(bw * 16 + lr) * kH + kw * 256 + lq * 8;
    f16x8 ha0, ha1, ha2, ha3, ha4, ha5, ha6, ha7;
    HLOAD(ha0, hp, 0);   HLOAD(ha1, hp, 64);  HLOAD(ha2, hp, 128);
    HLOAD(ha3, hp, 192); HLOAD(ha4, hp, 256); HLOAD(ha5, hp, 320);
    HLOAD(ha6, hp, 384); HLOAD(ha7, hp, 448);
    asm volatile("s_waitcnt vmcnt(0)" ::: "memory");
    __builtin_amdgcn_sched_barrier(0);

    // ---- partial z for this K-chunk: 16 MFMAs ----
    f32x4 acc0 = {}, acc1 = {};
    const int kkb = kw * 8;
#define KSTEP(ii, hareg)                                                     \
    {                                                                        \
      const f16x8 b0 = *(const f16x8*)&Ul[((kkb + ii) * 64 + l) * 8];        \
      const f16x8 b1 = *(const f16x8*)&Ul[((2048 + (kkb + ii) * 64) + l) * 8];\
      acc0 = MFMA16(hareg, b0, acc0);                                        \
      acc1 = MFMA16(hareg, b1, acc1);                                        \
    }
    KSTEP(0, ha0) KSTEP(1, ha1) KSTEP(2, ha2) KSTEP(3, ha3)
    KSTEP(4, ha4) KSTEP(5, ha5) KSTEP(6, ha6) KSTEP(7, ha7)
#undef KSTEP

    // ---- K-split reduction through LDS ----
    *(f32x4*)&red0[tid * 4] = acc0;
    *(f32x4*)&red1[tid * 4] = acc1;
    __syncthreads();

    if (kw == 0) {
      // ---- finalize: reduce partials, gates, write h ----
      f32x4 s0 = {}, s1 = {};
#pragma unroll
      for (int q = 0; q < 4; ++q) {
        s0 += *(const f32x4*)&red0[((q * 4 + bw) * 64 + l) * 4];
        s1 += *(const f32x4*)&red1[((q * 4 + bw) * 64 + l) * 4];
      }

      float hv[4];
#pragma unroll
      for (int j = 0; j < 4; ++j) {
        const f16* xb = &xzb[t & 1][(brow + j) * 32];
        const float z0 = s0[j] + (float)xb[lr];
        const float z1 = s1[j] + (float)xb[16 + lr];
        const float q0 = __shfl_xor(z0, 8);
        const float q1 = __shfl_xor(z1, 8);
        const float zi = (lr & 8) ? q0 : z0;
        const float zf = (lr & 8) ? z0 : q0;
        const float zg = (lr & 8) ? q1 : z1;
        const float zo = (lr & 8) ? z1 : q1;
        const float iv = fast_sigmoid(zi);
        const float fv = fast_sigmoid(zf);
        const float gv = fast_tanh(zg);
        const float ov = fast_sigmoid(zo);
        const float cn = fv * c_reg[j] + iv * gv;
        c_reg[j] = cn;
        hv[j] = ov * fast_tanh(cn);
      }

      if (lr < 8) {
#pragma unroll
        for (int j = 0; j < 4; ++j) {
          const int b = brow + j;
          const f16 hh = (f16)hv[j];
          const unsigned bits = (unsigned)__builtin_bit_cast(unsigned short, hh);
          f16* hp_out = hout + (size_t)b * kH + ugl;
          asm volatile("global_store_short %0, %1, off sc0 sc1"
                       :: "v"(hp_out), "v"(bits) : "memory");
          if (seq_out) seq_out[((size_t)b * kT + t) * kH + ugl] = hh;
          if (out32) out32[((size_t)b * kT + t) * kH + ugl] = hv[j];
        }
      }
      // drain h stores to coherent point before signaling (per-wave vmcnt:
      // does NOT wait on other waves' xz prefetch)
      asm volatile("s_waitcnt vmcnt(0)" ::: "memory");
    } else if (kw == 1 && t + 1 < kT) {
      // ---- prefetch xz(t+1) into the other LDS buffer ----
      f16x8 v = *(const f16x8*)(xzp + ((size_t)wg * kT + (t + 1)) * 2048 + pidx * 8);
      *(f16x8*)&xzb[(t + 1) & 1][pidx * 8] = v;
    }

    // ---- device-wide epoch barrier (no cache flushes) ----
    if (t + 1 < kT) {
      __syncthreads();
      if (tid == 0) {
        // fire-and-forget arrival (no-return atomic: ~half RTT)
        (void)__hip_atomic_fetch_add(bar, 1, __ATOMIC_RELAXED,
                                     __HIP_MEMORY_SCOPE_AGENT);
        const int target = kNWG * (t + 1);
        while (__hip_atomic_load(bar, __ATOMIC_RELAXED,
                                 __HIP_MEMORY_SCOPE_AGENT) < target)
          __builtin_amdgcn_s_sleep(1);
      }
      __syncthreads();
    }
  }
}

// ---------------- host launch ----------------
extern "C" void kernel_launch(void* const* d_in, const int* in_sizes, int n_in,
                              void* d_out, int out_size, void* d_ws, size_t ws_size,
                              hipStream_t stream) {
  (void)in_sizes; (void)n_in; (void)out_size; (void)ws_size;
  const float* x = (const float*)d_in[0];
  const float* Ws = (const float*)d_in[1];
  const float* Us = (const float*)d_in[2];
  const float* bs = (const float*)d_in[3];
  char* ws = (char*)d_ws;

  const size_t WT_OFF = 0;                                  // per-layer Wt (8 MB)
  const size_t UT_OFF = WT_OFF + (size_t)kG * kD * 2;       // per-layer Ut (8 MB)
  const size_t SA_OFF = UT_OFF + (size_t)kG * kD * 2;       // seq ping (32 MB)
  const size_t SB_OFF = SA_OFF + (size_t)kM * kD * 2;       // seq pong (32 MB)
  const size_t XZ_OFF = SB_OFF + (size_t)kM * kD * 2;       // xz permuted (128 MB)
  const size_t HA_OFF = XZ_OFF + (size_t)kM * kG * 2;       // h ping (128 KB)
  const size_t HB_OFF = HA_OFF + (size_t)kB * kH * 2;       // h pong (128 KB)
  const size_t BAR_OFF = HB_OFF + (size_t)kB * kH * 2;      // barrier counter

  f16* Wt = (f16*)(ws + WT_OFF);
  f16* Ut = (f16*)(ws + UT_OFF);
  f16* sA = (f16*)(ws + SA_OFF);
  f16* sB = (f16*)(ws + SB_OFF);
  f16* xz = (f16*)(ws + XZ_OFF);
  f16* hA = (f16*)(ws + HA_OFF);
  f16* hB = (f16*)(ws + HB_OFF);
  int* bar = (int*)(ws + BAR_OFF);

  cvt_f32_f16<<<kM * kD / (256 * 8), 256, 0, stream>>>(x, sA);

  f16* sin_ = sA;
  f16* sout_ = sB;
  for (int lyr = 0; lyr < kL; ++lyr) {
    transpose_cvt<<<dim3(kG / 32, kD / 32), dim3(32, 8), 0, stream>>>(
        Ws + (size_t)lyr * kD * kG, Wt);
    transpose_cvt<<<dim3(kG / 32, kD / 32), dim3(32, 8), 0, stream>>>(
        Us + (size_t)lyr * kH * kG, Ut);
    gemm_xw<<<dim3(kG / 128, kM / 128), 256, 0, stream>>>(
        sin_, Wt, bs + (size_t)lyr * kG, xz);
    hipMemsetAsync(ws + HA_OFF, 0, (size_t)kB * kH * 2 * 2 + 256, stream);
    lstm_scan<<<kNWG, 1024, 0, stream>>>(
        xz, Ut, hA, hB,
        (lyr < kL - 1) ? sout_ : (f16*)nullptr,
        (lyr == kL - 1) ? (float*)d_out : (float*)nullptr, bar);
    f16* tmp = sin_; sin_ = sout_; sout_ = tmp;
  }
}

// Round 5
// 8412.275 us; speedup vs baseline: 4.0860x; 1.0008x over previous
//
#include <hip/hip_runtime.h>
#include <stdint.h>
#include <stddef.h>

typedef _Float16 f16;
typedef _Float16 f16x8 __attribute__((ext_vector_type(8)));
typedef float f32x4 __attribute__((ext_vector_type(4)));

#define MFMA16(a, b, c) __builtin_amdgcn_mfma_f32_16x16x32_f16((a), (b), (c), 0, 0, 0)

static constexpr int kB = 64;
static constexpr int kT = 256;
static constexpr int kD = 1024;
static constexpr int kH = 1024;
static constexpr int kL = 4;
static constexpr int kM = kB * kT;   // 16384
static constexpr int kG = 4 * kH;    // 4096
static constexpr int kNWG = 128;     // scan workgroups

__device__ __forceinline__ float fast_sigmoid(float x) {
  return __builtin_amdgcn_rcpf(1.f + __expf(-x));
}
__device__ __forceinline__ float fast_tanh(float x) {
  x = fminf(9.f, fmaxf(-9.f, x));
  const float e = __expf(2.f * x);
  return (e - 1.f) * __builtin_amdgcn_rcpf(e + 1.f);
}

// ---------------- f32 -> f16 flat convert (8 elems/thread) ----------------
__global__ void cvt_f32_f16(const float* __restrict__ src, f16* __restrict__ dst) {
  size_t i = ((size_t)blockIdx.x * blockDim.x + threadIdx.x) * 8;
  float4 a = *(const float4*)(src + i);
  float4 b = *(const float4*)(src + i + 4);
  f16x8 o;
  o[0] = (f16)a.x; o[1] = (f16)a.y; o[2] = (f16)a.z; o[3] = (f16)a.w;
  o[4] = (f16)b.x; o[5] = (f16)b.y; o[6] = (f16)b.z; o[7] = (f16)b.w;
  *(f16x8*)(dst + i) = o;
}

// ---- transpose+convert one layer: [1024][4096] f32 -> [4096][1024] f16 ----
__global__ void transpose_cvt(const float* __restrict__ src, f16* __restrict__ dst) {
  __shared__ float tile[32][33];
  int c0 = blockIdx.x * 32;
  int r0 = blockIdx.y * 32;
  for (int rr = threadIdx.y; rr < 32; rr += 8)
    tile[rr][threadIdx.x] = src[(size_t)(r0 + rr) * kG + c0 + threadIdx.x];
  __syncthreads();
  for (int cc = threadIdx.y; cc < 32; cc += 8)
    dst[(size_t)(c0 + cc) * kD + r0 + threadIdx.x] = (f16)tile[threadIdx.x][cc];
}

// ---------------- input projection GEMM: xz = A @ Bt^T + bias ----------------
// Output written PERMUTED for the scan: xzp[wg][t][b][g*8+hh]
__launch_bounds__(256, 2)
__global__ void gemm_xw(const f16* __restrict__ A,
                        const f16* __restrict__ Bt,
                        const float* __restrict__ bias,
                        f16* __restrict__ xzp) {
  constexpr int K = 1024;
  constexpr int LDS_S = 40;
  __shared__ f16 As[128 * LDS_S];
  __shared__ f16 Bs[128 * LDS_S];
  const int n0 = blockIdx.x * 128;
  const int m0 = blockIdx.y * 128;
  const int tid = threadIdx.x;
  const int l = tid & 63, w = tid >> 6;
  const int lr = l & 15, lq = l >> 4;
  const int wm = (w & 1) * 64, wn = (w >> 1) * 64;

  const int srow = tid >> 1;
  const int skoff = (tid & 1) * 16;
  const f16* Ag = A + (size_t)(m0 + srow) * K + skoff;
  const f16* Bg = Bt + (size_t)(n0 + srow) * K + skoff;
  f16* Asw = &As[srow * LDS_S + skoff];
  f16* Bsw = &Bs[srow * LDS_S + skoff];

  f32x4 acc[4][4] = {};

  f16x8 pa0 = *(const f16x8*)(Ag), pa1 = *(const f16x8*)(Ag + 8);
  f16x8 pb0 = *(const f16x8*)(Bg), pb1 = *(const f16x8*)(Bg + 8);

#pragma unroll 1
  for (int kt = 0; kt < K / 32; ++kt) {
    __syncthreads();
    *(f16x8*)(Asw) = pa0; *(f16x8*)(Asw + 8) = pa1;
    *(f16x8*)(Bsw) = pb0; *(f16x8*)(Bsw + 8) = pb1;
    __syncthreads();
    if (kt + 1 < K / 32) {
      const f16* An = Ag + (kt + 1) * 32;
      const f16* Bn = Bg + (kt + 1) * 32;
      pa0 = *(const f16x8*)(An); pa1 = *(const f16x8*)(An + 8);
      pb0 = *(const f16x8*)(Bn); pb1 = *(const f16x8*)(Bn + 8);
    }
    f16x8 af[4], bf[4];
#pragma unroll
    for (int mt = 0; mt < 4; ++mt)
      af[mt] = *(const f16x8*)(&As[(wm + mt * 16 + lr) * LDS_S + lq * 8]);
#pragma unroll
    for (int nt = 0; nt < 4; ++nt)
      bf[nt] = *(const f16x8*)(&Bs[(wn + nt * 16 + lr) * LDS_S + lq * 8]);
#pragma unroll
    for (int mt = 0; mt < 4; ++mt)
#pragma unroll
      for (int nt = 0; nt < 4; ++nt)
        acc[mt][nt] = MFMA16(af[mt], bf[nt], acc[mt][nt]);
  }

#pragma unroll
  for (int nt = 0; nt < 4; ++nt) {
    const int col = n0 + wn + nt * 16 + lr;
    const float bv = bias[col];
    const int g = col >> 10, u = col & 1023;
    const int wgi = u >> 3;
    const int goff = (g << 3) | (u & 7);
#pragma unroll
    for (int mt = 0; mt < 4; ++mt) {
#pragma unroll
      for (int j = 0; j < 4; ++j) {
        const int row = m0 + wm + mt * 16 + lq * 4 + j;
        const int b = row >> 8, tt = row & 255;
        xzp[(((size_t)wgi * kT + tt) * 64 + b) * 32 + goff] =
            (f16)(acc[mt][nt][j] + bv);
      }
    }
  }
}

// ---------------- persistent LSTM scan v4: barrier-free dataflow ----------------
// 128 WGs x 1024 thr (16 waves: 4 batch-groups(bw) x 4 K-split groups(kw)).
// WG owns 8 h-units. U slice (64 KB) in LDS. h history: write-once slots
// h_hist[t][64][1024]. Readiness: flags[wg][bw] (own 64B line each) written
// after vmcnt(0) drain of the h stores. Consumer wave (bw,kw) polls the 32
// flags of WGs [kw*32, kw*32+32) with a single wave-parallel dword gather.
// No atomics, no device-wide barrier, 1 __syncthreads per step.
#define HLOAD(dst, base, imm)                                               \
  asm volatile("global_load_dwordx4 %0, %1, off offset:" #imm " sc0 sc1"    \
               : "=v"(dst) : "v"(base) : "memory")

__launch_bounds__(1024, 1)
__global__ void lstm_scan(const f16* __restrict__ xzp,   // permuted xz
                          const f16* __restrict__ Ut,    // [4096][1024] f16
                          f16* __restrict__ h_hist,      // [kT][64][1024] f16
                          int* __restrict__ flags,       // [128][4] x 16 ints
                          f16* __restrict__ seq_out,     // [kM][1024] f16 or null
                          float* __restrict__ out32) {   // [kM*1024] f32 or null
  // LDS: 64 KB U + 2x2x16 KB reduction (parity dbuf) + 8 KB xz dbuf = 136 KB.
  __shared__ f16 Ul[4096 * 8];
  __shared__ float red0[2][16 * 64 * 4];
  __shared__ float red1[2][16 * 64 * 4];
  __shared__ f16 xzb[2][2048];

  const int wg = blockIdx.x;
  const int hbase = wg * 8;
  const int tid = threadIdx.x;
  const int l = tid & 63, w = tid >> 6;
  const int lr = l & 15, lq = l >> 4;
  const int bw = w & 3;     // batch group: rows bw*16..bw*16+15
  const int kw = w >> 2;    // K group: k in [kw*256, kw*256+256)

  // ---- stage U fragments into LDS (once) ----
#pragma unroll
  for (int ff = 0; ff < 4; ++ff) {
    const int f = tid * 4 + ff;
    const int x = f >> 11, kk = (f >> 6) & 31, fl = f & 63;
    const int flr = fl & 15, flq = fl >> 4;
    const int r = x * 16 + flr;
    const size_t grow = (size_t)((r >> 3) * 1024 + hbase + (r & 7));
    *(f16x8*)&Ul[f * 8] = *(const f16x8*)(Ut + grow * 1024 + kk * 32 + flq * 8);
  }
  // ---- stage xz(t=0) into LDS buffer 0 ----
  const int pidx = (w - 4) * 64 + l;    // valid for kw==1 waves: 0..255
  if (kw == 1) {
    *(f16x8*)&xzb[0][pidx * 8] =
        *(const f16x8*)(xzp + ((size_t)wg * kT + 0) * 2048 + pidx * 8);
  }
  __syncthreads();

  const int brow = bw * 16 + lq * 4;
  const int ugl = hbase + (lr & 7);
  // flag this wave polls: producers p = kw*32 + (l&31), sub-flag bw
  const int* fpoll = flags + (((kw * 32 + (l & 31)) * 4 + bw) * 16);
  // flag this wave (if gate wave) publishes
  int* fpub = flags + ((wg * 4 + bw) * 16);

  float c_reg[4] = {0.f, 0.f, 0.f, 0.f};

#pragma unroll 1
  for (int t = 0; t < kT; ++t) {
    // ---- early xz(t+1) global load (latency hides under poll+MFMA) ----
    f16x8 xzv;
    if (kw == 1 && t + 1 < kT)
      xzv = *(const f16x8*)(xzp + ((size_t)wg * kT + (t + 1)) * 2048 + pidx * 8);

    // ---- wait for my producers' flags (wave-parallel gather) ----
    if (t > 0) {
      for (;;) {
        int fv;
        asm volatile("global_load_dword %0, %1, off sc0 sc1\n\t"
                     "s_waitcnt vmcnt(0)"
                     : "=v"(fv) : "v"(fpoll) : "memory");
        if (__all(fv >= t)) break;
      }
    }

    // ---- h loads from slot t (coherent) ----
    const f16* hp = h_hist + ((size_t)t * kB + bw * 16 + lr) * kH + kw * 256 + lq * 8;
    f16x8 ha0, ha1, ha2, ha3, ha4, ha5, ha6, ha7;
    HLOAD(ha0, hp, 0);   HLOAD(ha1, hp, 64);  HLOAD(ha2, hp, 128);
    HLOAD(ha3, hp, 192); HLOAD(ha4, hp, 256); HLOAD(ha5, hp, 320);
    HLOAD(ha6, hp, 384); HLOAD(ha7, hp, 448);
    asm volatile("s_waitcnt vmcnt(0)" ::: "memory");
    __builtin_amdgcn_sched_barrier(0);

    // ---- partial z for this K-chunk: 16 MFMAs ----
    f32x4 acc0 = {}, acc1 = {};
    const int kkb = kw * 8;
#define KSTEP(ii, hareg)                                                     \
    {                                                                        \
      const f16x8 b0 = *(const f16x8*)&Ul[((kkb + ii) * 64 + l) * 8];        \
      const f16x8 b1 = *(const f16x8*)&Ul[((2048 + (kkb + ii) * 64) + l) * 8];\
      acc0 = MFMA16(hareg, b0, acc0);                                        \
      acc1 = MFMA16(hareg, b1, acc1);                                        \
    }
    KSTEP(0, ha0) KSTEP(1, ha1) KSTEP(2, ha2) KSTEP(3, ha3)
    KSTEP(4, ha4) KSTEP(5, ha5) KSTEP(6, ha6) KSTEP(7, ha7)
#undef KSTEP

    // ---- K-split partials -> LDS (parity double-buffered) ----
    *(f32x4*)&red0[t & 1][tid * 4] = acc0;
    *(f32x4*)&red1[t & 1][tid * 4] = acc1;
    if (kw == 1 && t + 1 < kT)
      *(f16x8*)&xzb[(t + 1) & 1][pidx * 8] = xzv;
    __syncthreads();

    if (kw == 0) {
      // ---- finalize: reduce partials, gates, publish h ----
      f32x4 s0 = {}, s1 = {};
#pragma unroll
      for (int q = 0; q < 4; ++q) {
        s0 += *(const f32x4*)&red0[t & 1][((q * 4 + bw) * 64 + l) * 4];
        s1 += *(const f32x4*)&red1[t & 1][((q * 4 + bw) * 64 + l) * 4];
      }

      float hv[4];
#pragma unroll
      for (int j = 0; j < 4; ++j) {
        const f16* xb = &xzb[t & 1][(brow + j) * 32];
        const float z0 = s0[j] + (float)xb[lr];
        const float z1 = s1[j] + (float)xb[16 + lr];
        const float q0 = __shfl_xor(z0, 8);
        const float q1 = __shfl_xor(z1, 8);
        const float zi = (lr & 8) ? q0 : z0;
        const float zf = (lr & 8) ? z0 : q0;
        const float zg = (lr & 8) ? q1 : z1;
        const float zo = (lr & 8) ? z1 : q1;
        const float iv = fast_sigmoid(zi);
        const float fv = fast_sigmoid(zf);
        const float gv = fast_tanh(zg);
        const float ov = fast_sigmoid(zo);
        const float cn = fv * c_reg[j] + iv * gv;
        c_reg[j] = cn;
        hv[j] = ov * fast_tanh(cn);
      }

      // critical-path h stores first
      if (t + 1 < kT && lr < 8) {
#pragma unroll
        for (int j = 0; j < 4; ++j) {
          const f16 hh = (f16)hv[j];
          const unsigned bits = (unsigned)__builtin_bit_cast(unsigned short, hh);
          f16* hp_out = h_hist + ((size_t)(t + 1) * kB + brow + j) * kH + ugl;
          asm volatile("global_store_short %0, %1, off sc0 sc1"
                       :: "v"(hp_out), "v"(bits) : "memory");
        }
      }
      if (t + 1 < kT) {
        // drain h stores to coherent point, then publish readiness
        asm volatile("s_waitcnt vmcnt(0)" ::: "memory");
        if (l == 0) {
          const int val = t + 1;
          asm volatile("global_store_dword %0, %1, off sc0 sc1"
                       :: "v"(fpub), "v"(val) : "memory");
        }
      }
      // off-critical-path output stores
      if (lr < 8) {
#pragma unroll
        for (int j = 0; j < 4; ++j) {
          const int b = brow + j;
          if (seq_out) seq_out[((size_t)b * kT + t) * kH + ugl] = (f16)hv[j];
          if (out32) out32[((size_t)b * kT + t) * kH + ugl] = hv[j];
        }
      }
    }
  }
}

// ---------------- host launch ----------------
extern "C" void kernel_launch(void* const* d_in, const int* in_sizes, int n_in,
                              void* d_out, int out_size, void* d_ws, size_t ws_size,
                              hipStream_t stream) {
  (void)in_sizes; (void)n_in; (void)out_size; (void)ws_size;
  const float* x = (const float*)d_in[0];
  const float* Ws = (const float*)d_in[1];
  const float* Us = (const float*)d_in[2];
  const float* bs = (const float*)d_in[3];
  char* ws = (char*)d_ws;

  const size_t WT_OFF = 0;                                  // per-layer Wt (8 MB)
  const size_t UT_OFF = WT_OFF + (size_t)kG * kD * 2;       // per-layer Ut (8 MB)
  const size_t SA_OFF = UT_OFF + (size_t)kG * kD * 2;       // seq ping (32 MB)
  const size_t SB_OFF = SA_OFF + (size_t)kM * kD * 2;       // seq pong (32 MB)
  const size_t XZ_OFF = SB_OFF + (size_t)kM * kD * 2;       // xz permuted (128 MB)
  const size_t HH_OFF = XZ_OFF + (size_t)kM * kG * 2;       // h history (32 MB)
  const size_t FL_OFF = HH_OFF + (size_t)kT * kB * kH * 2;  // flags (32 KB)

  f16* Wt = (f16*)(ws + WT_OFF);
  f16* Ut = (f16*)(ws + UT_OFF);
  f16* sA = (f16*)(ws + SA_OFF);
  f16* sB = (f16*)(ws + SB_OFF);
  f16* xz = (f16*)(ws + XZ_OFF);
  f16* hh = (f16*)(ws + HH_OFF);
  int* fl = (int*)(ws + FL_OFF);

  cvt_f32_f16<<<kM * kD / (256 * 8), 256, 0, stream>>>(x, sA);

  f16* sin_ = sA;
  f16* sout_ = sB;
  for (int lyr = 0; lyr < kL; ++lyr) {
    transpose_cvt<<<dim3(kG / 32, kD / 32), dim3(32, 8), 0, stream>>>(
        Ws + (size_t)lyr * kD * kG, Wt);
    transpose_cvt<<<dim3(kG / 32, kD / 32), dim3(32, 8), 0, stream>>>(
        Us + (size_t)lyr * kH * kG, Ut);
    gemm_xw<<<dim3(kG / 128, kM / 128), 256, 0, stream>>>(
        sin_, Wt, bs + (size_t)lyr * kG, xz);
    // slot 0 = initial h zeros; flags = 0 (slot t ready when flag >= t)
    hipMemsetAsync(ws + HH_OFF, 0, (size_t)kB * kH * 2, stream);
    hipMemsetAsync(ws + FL_OFF, 0, kNWG * 4 * 16 * 4, stream);
    lstm_scan<<<kNWG, 1024, 0, stream>>>(
        xz, Ut, hh, fl,
        (lyr < kL - 1) ? sout_ : (f16*)nullptr,
        (lyr == kL - 1) ? (float*)d_out : (float*)nullptr);
    f16* tmp = sin_; sin_ = sout_; sout_ = tmp;
  }
}

// Round 6
// 7982.527 us; speedup vs baseline: 4.3059x; 1.0538x over previous
//
#include <hip/hip_runtime.h>
#include <stdint.h>
#include <stddef.h>

typedef _Float16 f16;
typedef _Float16 f16x8 __attribute__((ext_vector_type(8)));
typedef float f32x4 __attribute__((ext_vector_type(4)));

#define MFMA16(a, b, c) __builtin_amdgcn_mfma_f32_16x16x32_f16((a), (b), (c), 0, 0, 0)

static constexpr int kB = 64;
static constexpr int kT = 256;
static constexpr int kD = 1024;
static constexpr int kH = 1024;
static constexpr int kL = 4;
static constexpr int kM = kB * kT;   // 16384
static constexpr int kG = 4 * kH;    // 4096
static constexpr int kNWG = 128;     // scan workgroups

__device__ __forceinline__ float fast_sigmoid(float x) {
  return __builtin_amdgcn_rcpf(1.f + __expf(-x));
}
__device__ __forceinline__ float fast_tanh(float x) {
  x = fminf(9.f, fmaxf(-9.f, x));
  const float e = __expf(2.f * x);
  return (e - 1.f) * __builtin_amdgcn_rcpf(e + 1.f);
}

// ---------------- f32 -> f16 flat convert (8 elems/thread) ----------------
__global__ void cvt_f32_f16(const float* __restrict__ src, f16* __restrict__ dst) {
  size_t i = ((size_t)blockIdx.x * blockDim.x + threadIdx.x) * 8;
  float4 a = *(const float4*)(src + i);
  float4 b = *(const float4*)(src + i + 4);
  f16x8 o;
  o[0] = (f16)a.x; o[1] = (f16)a.y; o[2] = (f16)a.z; o[3] = (f16)a.w;
  o[4] = (f16)b.x; o[5] = (f16)b.y; o[6] = (f16)b.z; o[7] = (f16)b.w;
  *(f16x8*)(dst + i) = o;
}

// ---- transpose+convert one layer: [1024][4096] f32 -> [4096][1024] f16 ----
__global__ void transpose_cvt(const float* __restrict__ src, f16* __restrict__ dst) {
  __shared__ float tile[32][33];
  int c0 = blockIdx.x * 32;
  int r0 = blockIdx.y * 32;
  for (int rr = threadIdx.y; rr < 32; rr += 8)
    tile[rr][threadIdx.x] = src[(size_t)(r0 + rr) * kG + c0 + threadIdx.x];
  __syncthreads();
  for (int cc = threadIdx.y; cc < 32; cc += 8)
    dst[(size_t)(c0 + cc) * kD + r0 + threadIdx.x] = (f16)tile[threadIdx.x][cc];
}

// ---------------- input projection GEMM: xz = A @ Bt^T + bias ----------------
// Output written PERMUTED for the scan: xzp[wg][t][b][g*8+hh]
__launch_bounds__(256, 2)
__global__ void gemm_xw(const f16* __restrict__ A,
                        const f16* __restrict__ Bt,
                        const float* __restrict__ bias,
                        f16* __restrict__ xzp) {
  constexpr int K = 1024;
  constexpr int LDS_S = 40;
  __shared__ f16 As[128 * LDS_S];
  __shared__ f16 Bs[128 * LDS_S];
  const int n0 = blockIdx.x * 128;
  const int m0 = blockIdx.y * 128;
  const int tid = threadIdx.x;
  const int l = tid & 63, w = tid >> 6;
  const int lr = l & 15, lq = l >> 4;
  const int wm = (w & 1) * 64, wn = (w >> 1) * 64;

  const int srow = tid >> 1;
  const int skoff = (tid & 1) * 16;
  const f16* Ag = A + (size_t)(m0 + srow) * K + skoff;
  const f16* Bg = Bt + (size_t)(n0 + srow) * K + skoff;
  f16* Asw = &As[srow * LDS_S + skoff];
  f16* Bsw = &Bs[srow * LDS_S + skoff];

  f32x4 acc[4][4] = {};

  f16x8 pa0 = *(const f16x8*)(Ag), pa1 = *(const f16x8*)(Ag + 8);
  f16x8 pb0 = *(const f16x8*)(Bg), pb1 = *(const f16x8*)(Bg + 8);

#pragma unroll 1
  for (int kt = 0; kt < K / 32; ++kt) {
    __syncthreads();
    *(f16x8*)(Asw) = pa0; *(f16x8*)(Asw + 8) = pa1;
    *(f16x8*)(Bsw) = pb0; *(f16x8*)(Bsw + 8) = pb1;
    __syncthreads();
    if (kt + 1 < K / 32) {
      const f16* An = Ag + (kt + 1) * 32;
      const f16* Bn = Bg + (kt + 1) * 32;
      pa0 = *(const f16x8*)(An); pa1 = *(const f16x8*)(An + 8);
      pb0 = *(const f16x8*)(Bn); pb1 = *(const f16x8*)(Bn + 8);
    }
    f16x8 af[4], bf[4];
#pragma unroll
    for (int mt = 0; mt < 4; ++mt)
      af[mt] = *(const f16x8*)(&As[(wm + mt * 16 + lr) * LDS_S + lq * 8]);
#pragma unroll
    for (int nt = 0; nt < 4; ++nt)
      bf[nt] = *(const f16x8*)(&Bs[(wn + nt * 16 + lr) * LDS_S + lq * 8]);
#pragma unroll
    for (int mt = 0; mt < 4; ++mt)
#pragma unroll
      for (int nt = 0; nt < 4; ++nt)
        acc[mt][nt] = MFMA16(af[mt], bf[nt], acc[mt][nt]);
  }

#pragma unroll
  for (int nt = 0; nt < 4; ++nt) {
    const int col = n0 + wn + nt * 16 + lr;
    const float bv = bias[col];
    const int g = col >> 10, u = col & 1023;
    const int wgi = u >> 3;
    const int goff = (g << 3) | (u & 7);
#pragma unroll
    for (int mt = 0; mt < 4; ++mt) {
#pragma unroll
      for (int j = 0; j < 4; ++j) {
        const int row = m0 + wm + mt * 16 + lq * 4 + j;
        const int b = row >> 8, tt = row & 255;
        xzp[(((size_t)wgi * kT + tt) * 64 + b) * 32 + goff] =
            (f16)(acc[mt][nt][j] + bv);
      }
    }
  }
}

// ---------------- persistent LSTM scan v5: cached-h dataflow ----------------
// 128 WGs x 1024 thr (16 waves: 4 batch-groups(bw) x 4 K-split groups(kw)).
// Producers: sc0sc1 write-through h stores + vmcnt(0) drain + flag publish
//   (flags[wg]: one 64B line with 4 per-bw ints).
// Consumers: h loads are PLAIN CACHED (per-XCD L2 shares one fill across its
//   16 WGs; safe because slot t is write-once, first-touched after flag, and
//   dispatch-start acquire invalidated L2). Only waves 4..7 poll flags
//   (wave 4+c -> chunk c, one dwordx2 sc0sc1 per lane covers 32 producers x
//   4 sub-flags), then publish to LDS; all other waves spin on LDS.
__launch_bounds__(1024, 1)
__global__ void lstm_scan(const f16* __restrict__ xzp,   // permuted xz
                          const f16* __restrict__ Ut,    // [4096][1024] f16
                          f16* __restrict__ h_hist,      // [kT][64][1024] f16
                          int* __restrict__ flags,       // [128] x 16 ints
                          f16* __restrict__ seq_out,     // [kM][1024] f16 or null
                          float* __restrict__ out32) {   // [kM*1024] f32 or null
  __shared__ f16 Ul[4096 * 8];
  __shared__ float red0[2][16 * 64 * 4];
  __shared__ float red1[2][16 * 64 * 4];
  __shared__ f16 xzb[2][2048];
  __shared__ int lds_ready[4];

  const int wg = blockIdx.x;
  const int hbase = wg * 8;
  const int tid = threadIdx.x;
  const int l = tid & 63, w = tid >> 6;
  const int lr = l & 15, lq = l >> 4;
  const int bw = w & 3;     // batch group: rows bw*16..bw*16+15
  const int kw = w >> 2;    // K group: k in [kw*256, kw*256+256)

  if (tid < 4) lds_ready[tid] = 0;

  // ---- stage U fragments into LDS (once) ----
#pragma unroll
  for (int ff = 0; ff < 4; ++ff) {
    const int f = tid * 4 + ff;
    const int x = f >> 11, kk = (f >> 6) & 31, fl = f & 63;
    const int flr = fl & 15, flq = fl >> 4;
    const int r = x * 16 + flr;
    const size_t grow = (size_t)((r >> 3) * 1024 + hbase + (r & 7));
    *(f16x8*)&Ul[f * 8] = *(const f16x8*)(Ut + grow * 1024 + kk * 32 + flq * 8);
  }
  // ---- stage xz(t=0) into LDS buffer 0 ----
  const int pidx = (w - 4) * 64 + l;    // valid for kw==1 waves: 0..255
  if (kw == 1) {
    *(f16x8*)&xzb[0][pidx * 8] =
        *(const f16x8*)(xzp + ((size_t)wg * kT + 0) * 2048 + pidx * 8);
  }
  __syncthreads();

  const int brow = bw * 16 + lq * 4;
  const int ugl = hbase + (lr & 7);
  // poller (waves 4..7): chunk c = w-4; lane l checks producer c*32+(l>>1),
  // sub-flags (l&1)*2 and (l&1)*2+1 via one dwordx2.
  const int* fpoll = flags + ((((w - 4) * 32 + (l >> 1)) << 4) + ((l & 1) << 1));
  int* fpub = flags + ((wg << 4) + bw);   // gate wave bw publishes here

  float c_reg[4] = {0.f, 0.f, 0.f, 0.f};

#pragma unroll 1
  for (int t = 0; t < kT; ++t) {
    // ---- early xz(t+1) global load (plain; latency hides under sync) ----
    f16x8 xzv;
    if (kw == 1 && t + 1 < kT)
      xzv = *(const f16x8*)(xzp + ((size_t)wg * kT + (t + 1)) * 2048 + pidx * 8);

    // ---- readiness: waves 4..7 poll globally, publish to LDS; rest spin LDS
    if (t > 0) {
      if (kw == 1) {
        for (;;) {
          unsigned long long fv;
          asm volatile("global_load_dwordx2 %0, %1, off sc0 sc1\n\t"
                       "s_waitcnt vmcnt(0)"
                       : "=v"(fv) : "v"(fpoll) : "memory");
          if (__all((int)(fv & 0xffffffffu) >= t && (int)(fv >> 32) >= t))
            break;
        }
        *(volatile int*)&lds_ready[w - 4] = t;
      }
      volatile int* rdy = &lds_ready[kw];
      while (*rdy < t) __builtin_amdgcn_s_sleep(1);
      asm volatile("" ::: "memory");
    }

    // ---- h loads from slot t (PLAIN CACHED: L2-shared within XCD) ----
    const f16* hp = h_hist + ((size_t)t * kB + bw * 16 + lr) * kH + kw * 256 + lq * 8;
    const f16x8 ha0 = *(const f16x8*)(hp);
    const f16x8 ha1 = *(const f16x8*)(hp + 32);
    const f16x8 ha2 = *(const f16x8*)(hp + 64);
    const f16x8 ha3 = *(const f16x8*)(hp + 96);
    const f16x8 ha4 = *(const f16x8*)(hp + 128);
    const f16x8 ha5 = *(const f16x8*)(hp + 160);
    const f16x8 ha6 = *(const f16x8*)(hp + 192);
    const f16x8 ha7 = *(const f16x8*)(hp + 224);

    // ---- partial z for this K-chunk: 16 MFMAs ----
    f32x4 acc0 = {}, acc1 = {};
    const int kkb = kw * 8;
#define KSTEP(ii, hareg)                                                     \
    {                                                                        \
      const f16x8 b0 = *(const f16x8*)&Ul[((kkb + ii) * 64 + l) * 8];        \
      const f16x8 b1 = *(const f16x8*)&Ul[((2048 + (kkb + ii) * 64) + l) * 8];\
      acc0 = MFMA16(hareg, b0, acc0);                                        \
      acc1 = MFMA16(hareg, b1, acc1);                                        \
    }
    KSTEP(0, ha0) KSTEP(1, ha1) KSTEP(2, ha2) KSTEP(3, ha3)
    KSTEP(4, ha4) KSTEP(5, ha5) KSTEP(6, ha6) KSTEP(7, ha7)
#undef KSTEP

    // ---- gate waves pre-read xz(t) from LDS (xzb[t&1] stable until sync) ----
    float xzr0[4], xzr1[4];
    if (kw == 0) {
#pragma unroll
      for (int j = 0; j < 4; ++j) {
        const f16* xb = &xzb[t & 1][(brow + j) * 32];
        xzr0[j] = (float)xb[lr];
        xzr1[j] = (float)xb[16 + lr];
      }
    }

    // ---- K-split partials -> LDS (parity double-buffered) ----
    *(f32x4*)&red0[t & 1][tid * 4] = acc0;
    *(f32x4*)&red1[t & 1][tid * 4] = acc1;
    if (kw == 1 && t + 1 < kT)
      *(f16x8*)&xzb[(t + 1) & 1][pidx * 8] = xzv;
    __syncthreads();

    if (kw == 0) {
      // ---- finalize: reduce partials, gates, publish h ----
      f32x4 s0 = {}, s1 = {};
#pragma unroll
      for (int q = 0; q < 4; ++q) {
        s0 += *(const f32x4*)&red0[t & 1][((q * 4 + bw) * 64 + l) * 4];
        s1 += *(const f32x4*)&red1[t & 1][((q * 4 + bw) * 64 + l) * 4];
      }

      float hv[4];
#pragma unroll
      for (int j = 0; j < 4; ++j) {
        const float z0 = s0[j] + xzr0[j];
        const float z1 = s1[j] + xzr1[j];
        const float q0 = __shfl_xor(z0, 8);
        const float q1 = __shfl_xor(z1, 8);
        const float zi = (lr & 8) ? q0 : z0;
        const float zf = (lr & 8) ? z0 : q0;
        const float zg = (lr & 8) ? q1 : z1;
        const float zo = (lr & 8) ? z1 : q1;
        const float iv = fast_sigmoid(zi);
        const float fv = fast_sigmoid(zf);
        const float gv = fast_tanh(zg);
        const float ov = fast_sigmoid(zo);
        const float cn = fv * c_reg[j] + iv * gv;
        c_reg[j] = cn;
        hv[j] = ov * fast_tanh(cn);
      }

      // critical-path h stores first (write-through to coherent point)
      if (t + 1 < kT && lr < 8) {
#pragma unroll
        for (int j = 0; j < 4; ++j) {
          const f16 hh = (f16)hv[j];
          const unsigned bits = (unsigned)__builtin_bit_cast(unsigned short, hh);
          f16* hp_out = h_hist + ((size_t)(t + 1) * kB + brow + j) * kH + ugl;
          asm volatile("global_store_short %0, %1, off sc0 sc1"
                       :: "v"(hp_out), "v"(bits) : "memory");
        }
      }
      if (t + 1 < kT) {
        // drain h stores to coherent point, then publish readiness
        asm volatile("s_waitcnt vmcnt(0)" ::: "memory");
        if (l == 0) {
          const int val = t + 1;
          asm volatile("global_store_dword %0, %1, off sc0 sc1"
                       :: "v"(fpub), "v"(val) : "memory");
        }
      }
      // off-critical-path output stores (plain; flushed at dispatch end)
      if (lr < 8) {
#pragma unroll
        for (int j = 0; j < 4; ++j) {
          const int b = brow + j;
          if (seq_out) seq_out[((size_t)b * kT + t) * kH + ugl] = (f16)hv[j];
          if (out32) out32[((size_t)b * kT + t) * kH + ugl] = hv[j];
        }
      }
    }
  }
}

// ---------------- host launch ----------------
extern "C" void kernel_launch(void* const* d_in, const int* in_sizes, int n_in,
                              void* d_out, int out_size, void* d_ws, size_t ws_size,
                              hipStream_t stream) {
  (void)in_sizes; (void)n_in; (void)out_size; (void)ws_size;
  const float* x = (const float*)d_in[0];
  const float* Ws = (const float*)d_in[1];
  const float* Us = (const float*)d_in[2];
  const float* bs = (const float*)d_in[3];
  char* ws = (char*)d_ws;

  const size_t WT_OFF = 0;                                  // per-layer Wt (8 MB)
  const size_t UT_OFF = WT_OFF + (size_t)kG * kD * 2;       // per-layer Ut (8 MB)
  const size_t SA_OFF = UT_OFF + (size_t)kG * kD * 2;       // seq ping (32 MB)
  const size_t SB_OFF = SA_OFF + (size_t)kM * kD * 2;       // seq pong (32 MB)
  const size_t XZ_OFF = SB_OFF + (size_t)kM * kD * 2;       // xz permuted (128 MB)
  const size_t HH_OFF = XZ_OFF + (size_t)kM * kG * 2;       // h history (32 MB)
  const size_t FL_OFF = HH_OFF + (size_t)kT * kB * kH * 2;  // flags (8 KB)

  f16* Wt = (f16*)(ws + WT_OFF);
  f16* Ut = (f16*)(ws + UT_OFF);
  f16* sA = (f16*)(ws + SA_OFF);
  f16* sB = (f16*)(ws + SB_OFF);
  f16* xz = (f16*)(ws + XZ_OFF);
  f16* hh = (f16*)(ws + HH_OFF);
  int* fl = (int*)(ws + FL_OFF);

  cvt_f32_f16<<<kM * kD / (256 * 8), 256, 0, stream>>>(x, sA);

  f16* sin_ = sA;
  f16* sout_ = sB;
  for (int lyr = 0; lyr < kL; ++lyr) {
    transpose_cvt<<<dim3(kG / 32, kD / 32), dim3(32, 8), 0, stream>>>(
        Ws + (size_t)lyr * kD * kG, Wt);
    transpose_cvt<<<dim3(kG / 32, kD / 32), dim3(32, 8), 0, stream>>>(
        Us + (size_t)lyr * kH * kG, Ut);
    gemm_xw<<<dim3(kG / 128, kM / 128), 256, 0, stream>>>(
        sin_, Wt, bs + (size_t)lyr * kG, xz);
    // slot 0 = initial h zeros; flags = 0 (slot t ready when flag >= t)
    hipMemsetAsync(ws + HH_OFF, 0, (size_t)kB * kH * 2, stream);
    hipMemsetAsync(ws + FL_OFF, 0, kNWG * 16 * 4, stream);
    lstm_scan<<<kNWG, 1024, 0, stream>>>(
        xz, Ut, hh, fl,
        (lyr < kL - 1) ? sout_ : (f16*)nullptr,
        (lyr == kL - 1) ? (float*)d_out : (float*)nullptr);
    f16* tmp = sin_; sin_ = sout_; sout_ = tmp;
  }
}

// Round 7
// 5993.370 us; speedup vs baseline: 5.7351x; 1.3319x over previous
//
#include <hip/hip_runtime.h>
#include <stdint.h>
#include <stddef.h>

typedef _Float16 f16;
typedef _Float16 f16x8 __attribute__((ext_vector_type(8)));
typedef float f32x4 __attribute__((ext_vector_type(4)));
typedef int i32x4 __attribute__((ext_vector_type(4)));

#define MFMA16(a, b, c) __builtin_amdgcn_mfma_f32_16x16x32_f16((a), (b), (c), 0, 0, 0)

static constexpr int kB = 64;
static constexpr int kT = 256;
static constexpr int kD = 1024;
static constexpr int kH = 1024;
static constexpr int kG = 4096;
static constexpr int kSlot = 64 * 1024;          // f16 elems per h slot [64][1024]
static constexpr int kNSlots = kT + 1;           // 257 slots per layer

__device__ __forceinline__ float fast_sigmoid(float x) {
  return __builtin_amdgcn_rcpf(1.f + __expf(-x));
}
__device__ __forceinline__ float fast_tanh(float x) {
  x = fminf(9.f, fmaxf(-9.f, x));
  const float e = __expf(2.f * x);
  return (e - 1.f) * __builtin_amdgcn_rcpf(e + 1.f);
}

// ---- x [64][256][1024] f32 -> x_perm [256][64][1024] f16 ----
__global__ void x_perm_cvt(const float* __restrict__ x, f16* __restrict__ xp) {
  const size_t id = (size_t)blockIdx.x * 256 + threadIdx.x;
  const int d8 = (int)(id & 127) << 3;
  const int b = (int)(id >> 7) & 63;
  const int t = (int)(id >> 13);
  const float* s = x + (((size_t)b * kT + t) << 10) + d8;
  float4 a = *(const float4*)(s);
  float4 c = *(const float4*)(s + 4);
  f16x8 o;
  o[0] = (f16)a.x; o[1] = (f16)a.y; o[2] = (f16)a.z; o[3] = (f16)a.w;
  o[4] = (f16)c.x; o[5] = (f16)c.y; o[6] = (f16)c.z; o[7] = (f16)c.w;
  *(f16x8*)(xp + (((size_t)t * kB + b) << 10) + d8) = o;
}

// ---- transpose+convert 4 layers: [1024][4096] f32 -> [4096][1024] f16 ----
__global__ void transpose_cvt_z(const float* __restrict__ src, f16* __restrict__ dst) {
  __shared__ float tile[32][33];
  const int z = blockIdx.z;
  const int c0 = blockIdx.x * 32;
  const int r0 = blockIdx.y * 32;
  const float* s = src + (size_t)z * kD * kG;
  f16* d = dst + (size_t)z * kG * kD;
  for (int rr = threadIdx.y; rr < 32; rr += 8)
    tile[rr][threadIdx.x] = s[(size_t)(r0 + rr) * kG + c0 + threadIdx.x];
  __syncthreads();
  for (int cc = threadIdx.y; cc < 32; cc += 8)
    d[(size_t)(c0 + cc) * kD + r0 + threadIdx.x] = (f16)tile[threadIdx.x][cc];
}

// ---------------- 2-layer pipelined LSTM scan ----------------
// 256 WGs x 1024 thr. layerbit = bid&1 (0=lower, 1=upper), wgl = bid>>1 (0..127).
// WG owns 8 h-units (32 gate cols). Weights slice [W;U] (concat K=2048) in LDS
// (128 KB). z = below_h(t) @ W + own_h(t-1) @ U + bias. Lower layer's below =
// precomputed operand (x_perm or previous dispatch's h_hist), always ready.
// Upper layer's below = lower's h_hist slots, gated by lower's flags.
// 16 waves: bw = w&3 (16 batch rows), kw = w>>2 (512-wide chunk of concat-K;
// kw 0,1 -> W-term/below, kw 2,3 -> U-term/own).
// Flags: flags[layer][wgl*4+bw] int (packed 2 KB). Producer: sc0sc1 h stores
// -> vmcnt(0) -> flag store (proven r3-r6). Pollers: w==0 (below, upper only),
// w==8 (own) read all 512 ints with 2x dwordx4/lane, publish to LDS.
__launch_bounds__(1024, 1)
__global__ void lstm_scan2(const f16* __restrict__ below_lo,  // + t*kSlot = lower below operand
                           const f16* __restrict__ Wt_lo, const f16* __restrict__ Ut_lo,
                           const f16* __restrict__ Wt_hi, const f16* __restrict__ Ut_hi,
                           f16* __restrict__ hist_lo, f16* __restrict__ hist_hi,
                           int* __restrict__ flags_lo, int* __restrict__ flags_hi,
                           const float* __restrict__ bias_lo,
                           const float* __restrict__ bias_hi,
                           float* __restrict__ out32) {     // d_out or null
  __shared__ f16 Cw[8192 * 8];           // 128 KB: [2 colgrp][64 kstep][64 lane][8]
  __shared__ float red0[12 * 64 * 4];    // partials from kw=1,2,3 waves
  __shared__ float red1[12 * 64 * 4];
  __shared__ int lds_ready[2];

  const int bid = blockIdx.x;
  const int layerbit = bid & 1;
  const int wgl = bid >> 1;
  const int hbase = wgl * 8;
  const int tid = threadIdx.x;
  const int l = tid & 63, w = tid >> 6;
  const int lr = l & 15, lq = l >> 4;
  const int bw = w & 3, kw = w >> 2;

  const f16* Wt = layerbit ? Wt_hi : Wt_lo;
  const f16* Ut = layerbit ? Ut_hi : Ut_lo;
  f16* own_hist = layerbit ? hist_hi : hist_lo;
  const f16* below_base = layerbit ? (hist_lo + kSlot) : below_lo; // upper: slot t+1
  const int* fpoll_own = layerbit ? flags_hi : flags_lo;
  const int* fpoll_below = flags_lo;
  int* fpub = (layerbit ? flags_hi : flags_lo) + (wgl * 4 + bw);
  const float* bias = layerbit ? bias_hi : bias_lo;

  if (tid == 0) {
    lds_ready[0] = layerbit ? -1 : (1 << 30);  // lower's below always ready
    lds_ready[1] = 0;                          // own slot 0 pre-zeroed
  }

  // ---- stage weights slice into LDS: frag f: colgrp x=f>>12, kkg=(f>>6)&63,
  // lane fl=f&63. kkg<32 -> W (below term), kkg>=32 -> U (own term).
#pragma unroll
  for (int ff = 0; ff < 8; ++ff) {
    const int f = tid * 8 + ff;
    const int x = f >> 12, kkg = (f >> 6) & 63, fl = f & 63;
    const int flr = fl & 15, flq = fl >> 4;
    const int r = x * 16 + flr;
    const int grow = (r >> 3) * 1024 + hbase + (r & 7);
    const f16* src = (kkg < 32) ? Wt : Ut;
    *(f16x8*)&Cw[f * 8] =
        *(const f16x8*)(src + (size_t)grow * 1024 + (kkg & 31) * 32 + flq * 8);
  }

  // bias for finalize lanes
  float bv0 = 0.f, bv1 = 0.f;
  if (kw == 0) {
    bv0 = bias[((lr < 8) ? 0 : 1024) + hbase + (lr & 7)];
    bv1 = bias[((lr < 8) ? 2048 : 3072) + hbase + (lr & 7)];
  }
  __syncthreads();

  const int brow = bw * 16 + lq * 4;
  const int ugl = hbase + (lr & 7);
  const int* pollp = ((w == 0) ? fpoll_below : fpoll_own) + l * 8;

  float c_reg[4] = {0.f, 0.f, 0.f, 0.f};

#pragma unroll 1
  for (int t = 0; t < kT; ++t) {
    // ---- readiness ----
    if (w == 0) {
      if (layerbit) {
        const int tgt = t + 1;
        for (;;) {
          i32x4 pa, pb;
          asm volatile("global_load_dwordx4 %0, %2, off sc0 sc1\n\t"
                       "global_load_dwordx4 %1, %3, off sc0 sc1\n\t"
                       "s_waitcnt vmcnt(0)"
                       : "=v"(pa), "=v"(pb) : "v"(pollp), "v"(pollp + 4) : "memory");
          const bool ok = pa[0] >= tgt && pa[1] >= tgt && pa[2] >= tgt && pa[3] >= tgt &&
                          pb[0] >= tgt && pb[1] >= tgt && pb[2] >= tgt && pb[3] >= tgt;
          if (__all(ok)) break;
          __builtin_amdgcn_s_sleep(2);
        }
        __asm__ __volatile__("" ::: "memory");
        *(volatile int*)&lds_ready[0] = t;
      }
    } else if (w == 8) {
      const int tgt = t;
      for (;;) {
        i32x4 pa, pb;
        asm volatile("global_load_dwordx4 %0, %2, off sc0 sc1\n\t"
                     "global_load_dwordx4 %1, %3, off sc0 sc1\n\t"
                     "s_waitcnt vmcnt(0)"
                     : "=v"(pa), "=v"(pb) : "v"(pollp), "v"(pollp + 4) : "memory");
        const bool ok = pa[0] >= tgt && pa[1] >= tgt && pa[2] >= tgt && pa[3] >= tgt &&
                        pb[0] >= tgt && pb[1] >= tgt && pb[2] >= tgt && pb[3] >= tgt;
        if (__all(ok)) break;
        __builtin_amdgcn_s_sleep(2);
      }
      __asm__ __volatile__("" ::: "memory");
      *(volatile int*)&lds_ready[1] = t;
    }
    {
      volatile int* rdy = &lds_ready[kw >> 1];
      while (*rdy < t) __builtin_amdgcn_s_sleep(1);
      __asm__ __volatile__("" ::: "memory");
    }

    // ---- operand h loads (plain cached; L2-shared within XCD) ----
    const f16* hsrc = (kw < 2) ? (below_base + (size_t)t * kSlot)
                               : (own_hist + (size_t)t * kSlot);
    const f16* hp = hsrc + (size_t)(bw * 16 + lr) * kH + (kw & 1) * 512 + lq * 8;

    // ---- 32 MFMAs over this wave's 512-wide K chunk ----
    f32x4 acc0 = {}, acc1 = {};
    const int kkb = kw * 16;
#pragma unroll
    for (int ii = 0; ii < 16; ++ii) {
      const f16x8 ha = *(const f16x8*)(hp + ii * 32);
      const f16x8 b0 = *(const f16x8*)&Cw[((kkb + ii) * 64 + l) * 8];
      const f16x8 b1 = *(const f16x8*)&Cw[((4096 + (kkb + ii) * 64) + l) * 8];
      acc0 = MFMA16(ha, b0, acc0);
      acc1 = MFMA16(ha, b1, acc1);
    }

    // ---- partials -> LDS (kw 1..3), then reduce in kw0 ----
    if (kw != 0) {
      const int rw = w - 4;    // 0..11
      *(f32x4*)&red0[(rw * 64 + l) * 4] = acc0;
      *(f32x4*)&red1[(rw * 64 + l) * 4] = acc1;
    }
    __syncthreads();

    f32x4 s0 = acc0, s1 = acc1;
    if (kw == 0) {
#pragma unroll
      for (int q = 0; q < 3; ++q) {
        s0 += *(const f32x4*)&red0[((q * 4 + bw) * 64 + l) * 4];
        s1 += *(const f32x4*)&red1[((q * 4 + bw) * 64 + l) * 4];
      }
    }
    __syncthreads();   // red reusable next step after kw0's reads completed

    if (kw == 0) {
      float hv[4];
#pragma unroll
      for (int j = 0; j < 4; ++j) {
        const float z0 = s0[j] + bv0;
        const float z1 = s1[j] + bv1;
        const float q0 = __shfl_xor(z0, 8);
        const float q1 = __shfl_xor(z1, 8);
        const float zi = (lr & 8) ? q0 : z0;
        const float zf = (lr & 8) ? z0 : q0;
        const float zg = (lr & 8) ? q1 : z1;
        const float zo = (lr & 8) ? z1 : q1;
        const float iv = fast_sigmoid(zi);
        const float fv = fast_sigmoid(zf);
        const float gv = fast_tanh(zg);
        const float ov = fast_sigmoid(zo);
        const float cn = fv * c_reg[j] + iv * gv;
        c_reg[j] = cn;
        hv[j] = ov * fast_tanh(cn);
      }

      // h stores (write-through to coherent point), slot t+1
      if (lr < 8) {
#pragma unroll
        for (int j = 0; j < 4; ++j) {
          const f16 hh = (f16)hv[j];
          const unsigned bits = (unsigned)__builtin_bit_cast(unsigned short, hh);
          f16* hp_out = own_hist + (size_t)(t + 1) * kSlot + (size_t)(brow + j) * kH + ugl;
          asm volatile("global_store_short %0, %1, off sc0 sc1"
                       :: "v"(hp_out), "v"(bits) : "memory");
        }
      }
      // drain, then publish flag
      asm volatile("s_waitcnt vmcnt(0)" ::: "memory");
      if (l == 0) {
        const int val = t + 1;
        asm volatile("global_store_dword %0, %1, off sc0 sc1"
                     :: "v"(fpub), "v"(val) : "memory");
      }
      // final output (layer 3 only), off critical path
      if (out32 && layerbit && lr < 8) {
#pragma unroll
        for (int j = 0; j < 4; ++j)
          out32[((size_t)(brow + j) * kT + t) * kH + ugl] = hv[j];
      }
    }
  }
}

// ---------------- host launch ----------------
extern "C" void kernel_launch(void* const* d_in, const int* in_sizes, int n_in,
                              void* d_out, int out_size, void* d_ws, size_t ws_size,
                              hipStream_t stream) {
  (void)in_sizes; (void)n_in; (void)out_size; (void)ws_size;
  const float* x = (const float*)d_in[0];
  const float* Ws = (const float*)d_in[1];
  const float* Us = (const float*)d_in[2];
  const float* bs = (const float*)d_in[3];
  char* ws = (char*)d_ws;

  const size_t kLayerW = (size_t)kG * kD * 2;               // 8 MB
  const size_t kHistL = (size_t)kNSlots * kSlot * 2;        // 33,685,504 B
  const size_t WT_OFF = 0;                                  // 32 MB
  const size_t UT_OFF = WT_OFF + 4 * kLayerW;               // 32 MB
  const size_t XP_OFF = UT_OFF + 4 * kLayerW;               // 32 MB
  const size_t HH_OFF = XP_OFF + (size_t)kT * kSlot * 2;    // 128.5 MB
  const size_t FL_OFF = HH_OFF + 4 * kHistL;                // 8 KB  (total ~224.6 MiB)

  f16* Wt = (f16*)(ws + WT_OFF);
  f16* Ut = (f16*)(ws + UT_OFF);
  f16* xp = (f16*)(ws + XP_OFF);
  f16* hh = (f16*)(ws + HH_OFF);
  int* fl = (int*)(ws + FL_OFF);

  f16* hist[4];
  for (int i = 0; i < 4; ++i) hist[i] = (f16*)(ws + HH_OFF + i * kHistL);

  x_perm_cvt<<<8192, 256, 0, stream>>>(x, xp);
  transpose_cvt_z<<<dim3(kG / 32, kD / 32, 4), dim3(32, 8), 0, stream>>>(Ws, Wt);
  transpose_cvt_z<<<dim3(kG / 32, kD / 32, 4), dim3(32, 8), 0, stream>>>(Us, Ut);
  // zero initial h slot of each layer + all flags
  for (int i = 0; i < 4; ++i)
    hipMemsetAsync(ws + HH_OFF + i * kHistL, 0, (size_t)kSlot * 2, stream);
  hipMemsetAsync(ws + FL_OFF, 0, 4 * 512 * 4, stream);

  // dispatch 1: layers 0 (lower) + 1 (upper)
  lstm_scan2<<<256, 1024, 0, stream>>>(
      xp, Wt, Ut, Wt + (size_t)kG * kD, Ut + (size_t)kG * kD,
      hist[0], hist[1], fl, fl + 512,
      bs, bs + kG, (float*)nullptr);
  // dispatch 2: layers 2 (lower, below = hist[1] slots t+1) + 3 (upper)
  lstm_scan2<<<256, 1024, 0, stream>>>(
      hist[1] + kSlot, Wt + 2 * (size_t)kG * kD, Ut + 2 * (size_t)kG * kD,
      Wt + 3 * (size_t)kG * kD, Ut + 3 * (size_t)kG * kD,
      hist[2], hist[3], fl + 1024, fl + 1536,
      bs + 2 * kG, bs + 3 * kG, (float*)d_out);
}

// Round 8
// 4088.341 us; speedup vs baseline: 8.4074x; 1.4660x over previous
//
#include <hip/hip_runtime.h>
#include <stdint.h>
#include <stddef.h>

typedef _Float16 f16;
typedef _Float16 f16x8 __attribute__((ext_vector_type(8)));
typedef float f32x4 __attribute__((ext_vector_type(4)));
typedef int i32x4 __attribute__((ext_vector_type(4)));

#define MFMA16(a, b, c) __builtin_amdgcn_mfma_f32_16x16x32_f16((a), (b), (c), 0, 0, 0)

static constexpr int kB = 64;
static constexpr int kT = 256;
static constexpr int kD = 1024;
static constexpr int kH = 1024;
static constexpr int kG = 4096;
static constexpr int kSlot = 64 * 1024;          // f16 elems per h slot [128][64][8]
static constexpr int kNSlots = kT + 1;           // 257 slots per layer

__device__ __forceinline__ float fast_sigmoid(float x) {
  return __builtin_amdgcn_rcpf(1.f + __expf(-x));
}
__device__ __forceinline__ float fast_tanh(float x) {
  x = fminf(9.f, fmaxf(-9.f, x));
  const float e = __expf(2.f * x);
  return (e - 1.f) * __builtin_amdgcn_rcpf(e + 1.f);
}

// ---- x [64][256][1024] f32 -> xp[t][owner=d>>3][b][d&7] f16 ----
__global__ void x_perm_cvt(const float* __restrict__ x, f16* __restrict__ xp) {
  const size_t id = (size_t)blockIdx.x * 256 + threadIdx.x;
  const int d8 = (int)(id & 127) << 3;
  const int b = (int)(id >> 7) & 63;
  const int t = (int)(id >> 13);
  const float* s = x + (((size_t)b * kT + t) << 10) + d8;
  float4 a = *(const float4*)(s);
  float4 c = *(const float4*)(s + 4);
  f16x8 o;
  o[0] = (f16)a.x; o[1] = (f16)a.y; o[2] = (f16)a.z; o[3] = (f16)a.w;
  o[4] = (f16)c.x; o[5] = (f16)c.y; o[6] = (f16)c.z; o[7] = (f16)c.w;
  *(f16x8*)(xp + (size_t)t * kSlot + (size_t)(d8 >> 3) * 512 + b * 8) = o;
}

// ---- transpose+convert 4 layers: [1024][4096] f32 -> [4096][1024] f16 ----
__global__ void transpose_cvt_z(const float* __restrict__ src, f16* __restrict__ dst) {
  __shared__ float tile[32][33];
  const int z = blockIdx.z;
  const int c0 = blockIdx.x * 32;
  const int r0 = blockIdx.y * 32;
  const float* s = src + (size_t)z * kD * kG;
  f16* d = dst + (size_t)z * kG * kD;
  for (int rr = threadIdx.y; rr < 32; rr += 8)
    tile[rr][threadIdx.x] = s[(size_t)(r0 + rr) * kG + c0 + threadIdx.x];
  __syncthreads();
  for (int cc = threadIdx.y; cc < 32; cc += 8)
    d[(size_t)(c0 + cc) * kD + r0 + threadIdx.x] = (f16)tile[threadIdx.x][cc];
}

// ---------------- 2-layer pipelined LSTM scan (owner-block h layout) --------
// 256 WGs x 1024 thr. layerbit = bid&1, wgl = bid>>1 owns units [wgl*8,+8).
// Weights slice [W;U] (concat K=2048) in LDS (128 KB).
// h slot layout: [owner(128)][row(64)][unit(8)] -> each 64B line is single-
// producer; publish = 1 dwordx4 sc0sc1 per lane (coalesced), no false sharing.
__launch_bounds__(1024, 1)
__global__ void lstm_scan2(const f16* __restrict__ below_lo,
                           const f16* __restrict__ Wt_lo, const f16* __restrict__ Ut_lo,
                           const f16* __restrict__ Wt_hi, const f16* __restrict__ Ut_hi,
                           f16* __restrict__ hist_lo, f16* __restrict__ hist_hi,
                           int* __restrict__ flags_lo, int* __restrict__ flags_hi,
                           const float* __restrict__ bias_lo,
                           const float* __restrict__ bias_hi,
                           float* __restrict__ out32) {
  __shared__ f16 Cw[8192 * 8];           // 128 KB
  __shared__ float red0[12 * 64 * 4];
  __shared__ float red1[12 * 64 * 4];
  __shared__ f16 hstage[4][16][8];       // per-gate-wave h gather (wave-local)
  __shared__ int lds_ready[2];

  const int bid = blockIdx.x;
  const int layerbit = bid & 1;
  const int wgl = bid >> 1;
  const int hbase = wgl * 8;
  const int tid = threadIdx.x;
  const int l = tid & 63, w = tid >> 6;
  const int lr = l & 15, lq = l >> 4;
  const int bw = w & 3, kw = w >> 2;

  const f16* Wt = layerbit ? Wt_hi : Wt_lo;
  const f16* Ut = layerbit ? Ut_hi : Ut_lo;
  f16* own_hist = layerbit ? hist_hi : hist_lo;
  const f16* below_base = layerbit ? (hist_lo + kSlot) : below_lo; // upper: slot t+1
  const int* fpoll_own = layerbit ? flags_hi : flags_lo;
  const int* fpoll_below = flags_lo;
  int* fpub = (layerbit ? flags_hi : flags_lo) + (wgl * 4 + bw);
  const float* bias = layerbit ? bias_hi : bias_lo;

  if (tid == 0) {
    lds_ready[0] = layerbit ? -1 : (1 << 30);  // lower's below always ready
    lds_ready[1] = 0;                          // own slot 0 pre-zeroed
  }

  // ---- stage weights slice into LDS ----
#pragma unroll
  for (int ff = 0; ff < 8; ++ff) {
    const int f = tid * 8 + ff;
    const int x = f >> 12, kkg = (f >> 6) & 63, fl = f & 63;
    const int flr = fl & 15, flq = fl >> 4;
    const int r = x * 16 + flr;
    const int grow = (r >> 3) * 1024 + hbase + (r & 7);
    const f16* src = (kkg < 32) ? Wt : Ut;
    *(f16x8*)&Cw[f * 8] =
        *(const f16x8*)(src + (size_t)grow * 1024 + (kkg & 31) * 32 + flq * 8);
  }

  float bv0 = 0.f, bv1 = 0.f;
  if (kw == 0) {
    bv0 = bias[((lr < 8) ? 0 : 1024) + hbase + (lr & 7)];
    bv1 = bias[((lr < 8) ? 2048 : 3072) + hbase + (lr & 7)];
  }
  __syncthreads();

  const int brow = bw * 16 + lq * 4;
  const int ugl = hbase + (lr & 7);
  const int* pollp = ((w == 0) ? fpoll_below : fpoll_own) + l * 8;
  const int row = bw * 16 + lr;

  float c_reg[4] = {0.f, 0.f, 0.f, 0.f};

#pragma unroll 1
  for (int t = 0; t < kT; ++t) {
    // ---- readiness ----
    if (w == 0) {
      if (layerbit) {
        const int tgt = t + 1;
        for (;;) {
          i32x4 pa, pb;
          asm volatile("global_load_dwordx4 %0, %2, off sc0 sc1\n\t"
                       "global_load_dwordx4 %1, %3, off sc0 sc1\n\t"
                       "s_waitcnt vmcnt(0)"
                       : "=v"(pa), "=v"(pb) : "v"(pollp), "v"(pollp + 4) : "memory");
          const bool ok = pa[0] >= tgt && pa[1] >= tgt && pa[2] >= tgt && pa[3] >= tgt &&
                          pb[0] >= tgt && pb[1] >= tgt && pb[2] >= tgt && pb[3] >= tgt;
          if (__all(ok)) break;
          __builtin_amdgcn_s_sleep(2);
        }
        __asm__ __volatile__("" ::: "memory");
        *(volatile int*)&lds_ready[0] = t;
      }
    } else if (w == 8) {
      const int tgt = t;
      for (;;) {
        i32x4 pa, pb;
        asm volatile("global_load_dwordx4 %0, %2, off sc0 sc1\n\t"
                     "global_load_dwordx4 %1, %3, off sc0 sc1\n\t"
                     "s_waitcnt vmcnt(0)"
                     : "=v"(pa), "=v"(pb) : "v"(pollp), "v"(pollp + 4) : "memory");
        const bool ok = pa[0] >= tgt && pa[1] >= tgt && pa[2] >= tgt && pa[3] >= tgt &&
                        pb[0] >= tgt && pb[1] >= tgt && pb[2] >= tgt && pb[3] >= tgt;
        if (__all(ok)) break;
        __builtin_amdgcn_s_sleep(2);
      }
      __asm__ __volatile__("" ::: "memory");
      *(volatile int*)&lds_ready[1] = t;
    }
    {
      volatile int* rdy = &lds_ready[kw >> 1];
      while (*rdy < t) __builtin_amdgcn_s_sleep(1);
      __asm__ __volatile__("" ::: "memory");
    }

    // ---- operand h loads (plain cached; owner-block layout) ----
    const f16* hsrc = (kw < 2) ? (below_base + (size_t)t * kSlot)
                               : (own_hist + (size_t)t * kSlot);
    // owner = (kw&1)*64 + ii*4 + lq ; element offset = owner*512 + row*8
    const f16* hp = hsrc + (size_t)((kw & 1) * 64 + lq) * 512 + row * 8;

    f32x4 acc0 = {}, acc1 = {};
    const int kkb = kw * 16;
#pragma unroll
    for (int ii = 0; ii < 16; ++ii) {
      const f16x8 ha = *(const f16x8*)(hp + ii * 2048);
      const f16x8 b0 = *(const f16x8*)&Cw[((kkb + ii) * 64 + l) * 8];
      const f16x8 b1 = *(const f16x8*)&Cw[((4096 + (kkb + ii) * 64) + l) * 8];
      acc0 = MFMA16(ha, b0, acc0);
      acc1 = MFMA16(ha, b1, acc1);
    }

    if (kw != 0) {
      const int rw = w - 4;    // 0..11
      *(f32x4*)&red0[(rw * 64 + l) * 4] = acc0;
      *(f32x4*)&red1[(rw * 64 + l) * 4] = acc1;
    }
    __syncthreads();

    f32x4 s0 = acc0, s1 = acc1;
    if (kw == 0) {
#pragma unroll
      for (int q = 0; q < 3; ++q) {
        s0 += *(const f32x4*)&red0[((q * 4 + bw) * 64 + l) * 4];
        s1 += *(const f32x4*)&red1[((q * 4 + bw) * 64 + l) * 4];
      }
    }
    __syncthreads();   // red reusable next step

    if (kw == 0) {
      float hv[4];
#pragma unroll
      for (int j = 0; j < 4; ++j) {
        const float z0 = s0[j] + bv0;
        const float z1 = s1[j] + bv1;
        const float q0 = __shfl_xor(z0, 8);
        const float q1 = __shfl_xor(z1, 8);
        const float zi = (lr & 8) ? q0 : z0;
        const float zf = (lr & 8) ? z0 : q0;
        const float zg = (lr & 8) ? q1 : z1;
        const float zo = (lr & 8) ? z1 : q1;
        const float iv = fast_sigmoid(zi);
        const float fv = fast_sigmoid(zf);
        const float gv = fast_tanh(zg);
        const float ov = fast_sigmoid(zo);
        const float cn = fv * c_reg[j] + iv * gv;
        c_reg[j] = cn;
        hv[j] = ov * fast_tanh(cn);
      }

      // gather this wave's 16 rows x 8 units into LDS (wave-local)
      if (lr < 8) {
#pragma unroll
        for (int j = 0; j < 4; ++j)
          hstage[w][lq * 4 + j][lr] = (f16)hv[j];
      }
      // coalesced publish: 1 dwordx4 sc0sc1 per lane (lanes 0..15)
      if (l < 16) {
        const f16x8 hrow = *(const f16x8*)&hstage[w][l][0];
        f16* dst = own_hist + (size_t)(t + 1) * kSlot +
                   ((size_t)wgl * 64 + bw * 16 + l) * 8;
        asm volatile("global_store_dwordx4 %0, %1, off sc0 sc1"
                     :: "v"(dst), "v"(hrow) : "memory");
      }
      asm volatile("s_waitcnt vmcnt(0)" ::: "memory");
      if (l == 0) {
        const int val = t + 1;
        asm volatile("global_store_dword %0, %1, off sc0 sc1"
                     :: "v"(fpub), "v"(val) : "memory");
      }
      // final output (layer 3 only), off critical path
      if (out32 && layerbit && lr < 8) {
#pragma unroll
        for (int j = 0; j < 4; ++j)
          out32[((size_t)(brow + j) * kT + t) * kH + ugl] = hv[j];
      }
    }
  }
}

// ---------------- host launch ----------------
extern "C" void kernel_launch(void* const* d_in, const int* in_sizes, int n_in,
                              void* d_out, int out_size, void* d_ws, size_t ws_size,
                              hipStream_t stream) {
  (void)in_sizes; (void)n_in; (void)out_size; (void)ws_size;
  const float* x = (const float*)d_in[0];
  const float* Ws = (const float*)d_in[1];
  const float* Us = (const float*)d_in[2];
  const float* bs = (const float*)d_in[3];
  char* ws = (char*)d_ws;

  const size_t kLayerW = (size_t)kG * kD * 2;               // 8 MB
  const size_t kHistL = (size_t)kNSlots * kSlot * 2;        // 33,685,504 B
  const size_t WT_OFF = 0;                                  // 32 MB
  const size_t UT_OFF = WT_OFF + 4 * kLayerW;               // 32 MB
  const size_t XP_OFF = UT_OFF + 4 * kLayerW;               // 32 MB
  const size_t HH_OFF = XP_OFF + (size_t)kT * kSlot * 2;    // 128.5 MB
  const size_t FL_OFF = HH_OFF + 4 * kHistL;                // 8 KB

  f16* Wt = (f16*)(ws + WT_OFF);
  f16* Ut = (f16*)(ws + UT_OFF);
  f16* xp = (f16*)(ws + XP_OFF);
  int* fl = (int*)(ws + FL_OFF);

  f16* hist[4];
  for (int i = 0; i < 4; ++i) hist[i] = (f16*)(ws + HH_OFF + i * kHistL);

  x_perm_cvt<<<8192, 256, 0, stream>>>(x, xp);
  transpose_cvt_z<<<dim3(kG / 32, kD / 32, 4), dim3(32, 8), 0, stream>>>(Ws, Wt);
  transpose_cvt_z<<<dim3(kG / 32, kD / 32, 4), dim3(32, 8), 0, stream>>>(Us, Ut);
  for (int i = 0; i < 4; ++i)
    hipMemsetAsync(ws + HH_OFF + i * kHistL, 0, (size_t)kSlot * 2, stream);
  hipMemsetAsync(ws + FL_OFF, 0, 4 * 512 * 4, stream);

  // dispatch 1: layers 0 (lower) + 1 (upper)
  lstm_scan2<<<256, 1024, 0, stream>>>(
      xp, Wt, Ut, Wt + (size_t)kG * kD, Ut + (size_t)kG * kD,
      hist[0], hist[1], fl, fl + 512,
      bs, bs + kG, (float*)nullptr);
  // dispatch 2: layers 2 (lower, below = hist[1] slots t+1) + 3 (upper)
  lstm_scan2<<<256, 1024, 0, stream>>>(
      hist[1] + kSlot, Wt + 2 * (size_t)kG * kD, Ut + 2 * (size_t)kG * kD,
      Wt + 3 * (size_t)kG * kD, Ut + 3 * (size_t)kG * kD,
      hist[2], hist[3], fl + 1024, fl + 1536,
      bs + 2 * kG, bs + 3 * kG, (float*)d_out);
}